// Round 3
// baseline (863.746 us; speedup 1.0000x reference)
//
#include <hip/hip_runtime.h>

#define N_NODES 100000
#define N_EDGES 3200000
#define DIM 128
#define HID 32

#define BSH 7                                   // bucket = dst >> 7
#define BNODES (1 << BSH)                       // 128 nodes per bucket
#define NBUK ((N_NODES + BNODES - 1) >> BSH)    // 782
#define NBP 1024                                // padded (pow2) bucket count
#define FCHUNK 8192                             // edges per partition block
#define NFILL ((N_EDGES + FCHUNK - 1) / FCHUNK) // 391

// Workspace: bcnt[NBP] boff[NBP] gcur[NBP] ebuf[E] dinv[N] y1[N*HID] y2[N]  (~26.4 MB)

__global__ void k_zeroB(int* __restrict__ bcnt) {
    int i = threadIdx.x;
    if (i < NBP) bcnt[i] = 0;
}

// global bucket histogram via per-block LDS histogram
__launch_bounds__(256)
__global__ void k_bhist(const int* __restrict__ dst, int* __restrict__ bcnt) {
    __shared__ int h[NBP];
    for (int i = threadIdx.x; i < NBP; i += 256) h[i] = 0;
    __syncthreads();
    int stride = gridDim.x * blockDim.x;
    for (int e = blockIdx.x * blockDim.x + threadIdx.x; e < N_EDGES; e += stride)
        atomicAdd(&h[dst[e] >> BSH], 1);
    __syncthreads();
    for (int i = threadIdx.x; i < NBP; i += 256)
        if (h[i]) atomicAdd(&bcnt[i], h[i]);
}

// single block: exclusive scan of bcnt[NBP] -> boff, working copy -> gcur
__global__ void k_bscan(const int* __restrict__ bcnt, int* __restrict__ boff,
                        int* __restrict__ gcur) {
    __shared__ int s[256];
    int t = threadIdx.x;
    int c[4]; int sum = 0;
    #pragma unroll
    for (int k = 0; k < 4; ++k) { c[k] = bcnt[t * 4 + k]; sum += c[k]; }
    s[t] = sum; __syncthreads();
    for (int d = 1; d < 256; d <<= 1) {
        int add = (t >= d) ? s[t - d] : 0;
        __syncthreads();
        s[t] += add;
        __syncthreads();
    }
    int excl = s[t] - sum;
    #pragma unroll
    for (int k = 0; k < 4; ++k) {
        boff[t * 4 + k] = excl;
        gcur[t * 4 + k] = excl;
        excl += c[k];
    }
}

// Partition edges into bucket-ordered ebuf with LDS staging + coalesced flush.
// packed edge = (dst & 127) << 20 | src   (src < 2^17)
__launch_bounds__(256)
__global__ void k_bfill(const int* __restrict__ src, const int* __restrict__ dst,
                        int* __restrict__ gcur, unsigned int* __restrict__ ebuf) {
    __shared__ int cntA[NBP];               // pass-1 counts (chunk-local)
    __shared__ int offA[NBP];               // exclusive offsets within chunk
    __shared__ int cntB[NBP];               // pass-2 cursors
    __shared__ int baseG[NBP];              // reserved global base per bucket
    __shared__ int ssum[256];
    __shared__ unsigned int stage[FCHUNK];  // 32 KB
    int t = threadIdx.x;
    int e0 = blockIdx.x * FCHUNK;
    int eN = min(e0 + FCHUNK, N_EDGES) - e0;
    for (int i = t; i < NBP; i += 256) { cntA[i] = 0; cntB[i] = 0; }
    __syncthreads();
    // pass 1: count buckets in this chunk
    for (int i = t; i < eN; i += 256)
        atomicAdd(&cntA[dst[e0 + i] >> BSH], 1);
    __syncthreads();
    // LDS exclusive scan cntA -> offA (4 elems/thread)
    {
        int c[4]; int sum = 0;
        #pragma unroll
        for (int k = 0; k < 4; ++k) { c[k] = cntA[t * 4 + k]; sum += c[k]; }
        ssum[t] = sum; __syncthreads();
        for (int d = 1; d < 256; d <<= 1) {
            int add = (t >= d) ? ssum[t - d] : 0;
            __syncthreads();
            ssum[t] += add;
            __syncthreads();
        }
        int excl = ssum[t] - sum;
        #pragma unroll
        for (int k = 0; k < 4; ++k) { offA[t * 4 + k] = excl; excl += c[k]; }
    }
    __syncthreads();
    // reserve global space per bucket (counts are final)
    for (int b = t; b < NBP; b += 256)
        if (cntA[b] > 0) baseG[b] = atomicAdd(&gcur[b], cntA[b]);
    // pass 2: re-read edges, place packed into LDS stage at bucket-local position
    for (int i = t; i < eN; i += 256) {
        int d = dst[e0 + i];
        int b = d >> BSH;
        unsigned int packed = ((unsigned int)(d & (BNODES - 1)) << 20)
                            | (unsigned int)src[e0 + i];
        int pos = offA[b] + atomicAdd(&cntB[b], 1);
        stage[pos] = packed;
    }
    __syncthreads();
    // coalesced flush: stage index i -> bucket via binary search (largest b: offA[b] <= i)
    for (int i = t; i < eN; i += 256) {
        int lo = 0, hi = NBP - 1;
        while (lo < hi) {
            int mid = (lo + hi + 1) >> 1;
            if (offA[mid] <= i) lo = mid; else hi = mid - 1;
        }
        ebuf[baseG[lo] + (i - offA[lo])] = stage[i];
    }
}

// per-bucket node in-degrees -> dinv = rsqrt(deg+1)
__launch_bounds__(256)
__global__ void k_bcount(const unsigned int* __restrict__ ebuf, const int* __restrict__ boff,
                         const int* __restrict__ bcnt, float* __restrict__ dinv) {
    __shared__ int cnt[BNODES];
    int t = threadIdx.x;
    if (t < BNODES) cnt[t] = 0;
    __syncthreads();
    int b = blockIdx.x;
    int s0 = boff[b], n = bcnt[b];
    for (int j = t; j < n; j += 256)
        atomicAdd(&cnt[ebuf[s0 + j] >> 20], 1);
    __syncthreads();
    int v = b * BNODES + t;
    if (t < BNODES && v < N_NODES) dinv[v] = rsqrtf((float)(cnt[t] + 1));
}

// y1[v][c] = dinv[v] * sum_k x[v][k] * W1[k][c]; 8 nodes x 32 cols per block
__launch_bounds__(256)
__global__ void k_gemm1(const float* __restrict__ x, const float* __restrict__ W1,
                        const float* __restrict__ dinv, float* __restrict__ y1) {
    __shared__ float Wl[DIM * HID];
    for (int i = threadIdx.x; i < DIM * HID; i += 256) Wl[i] = W1[i];
    __syncthreads();
    int node = blockIdx.x * 8 + (threadIdx.x >> 5);
    int col = threadIdx.x & 31;
    if (node >= N_NODES) return;
    const float4* x4 = (const float4*)(x + (size_t)node * DIM);
    float acc = 0.0f;
    #pragma unroll
    for (int k4 = 0; k4 < DIM / 4; ++k4) {
        float4 v = x4[k4];
        int k = k4 * 4;
        acc = fmaf(v.x, Wl[(k + 0) * HID + col], acc);
        acc = fmaf(v.y, Wl[(k + 1) * HID + col], acc);
        acc = fmaf(v.z, Wl[(k + 2) * HID + col], acc);
        acc = fmaf(v.w, Wl[(k + 3) * HID + col], acc);
    }
    y1[(size_t)node * HID + col] = dinv[node] * acc;
}

// Layer-1 aggregation per bucket: LDS accumulator [128 nodes][32 cols], lane = col.
// Fused epilogue: h = relu(dinv*(acc+self)+b1) -> out_h; y2 = dinv*(h.W2)
__launch_bounds__(256)
__global__ void k_gather1(const unsigned int* __restrict__ ebuf, const int* __restrict__ boff,
                          const int* __restrict__ bcnt, const float* __restrict__ y1,
                          const float* __restrict__ dinv, const float* __restrict__ b1,
                          const float* __restrict__ W2, float* __restrict__ out_h,
                          float* __restrict__ y2) {
    __shared__ float acc[BNODES * HID];   // 16 KB
    int t = threadIdx.x;
    int lane = t & 31;
    int grp = t >> 5;                     // 0..7
    for (int i = t; i < BNODES * HID; i += 256) acc[i] = 0.f;
    __syncthreads();
    int b = blockIdx.x;
    int s0 = boff[b], n = bcnt[b];
    for (int base = grp * 32; base < n; base += 8 * 32) {
        int m = min(32, n - base);
        unsigned int ej = 0;
        if (lane < m) ej = ebuf[s0 + base + lane];   // coalesced slab
        int k = 0;
        for (; k + 4 <= m; k += 4) {                 // 4 independent gathers in flight
            unsigned int v0 = __shfl(ej, k + 0, 32);
            unsigned int v1 = __shfl(ej, k + 1, 32);
            unsigned int v2 = __shfl(ej, k + 2, 32);
            unsigned int v3 = __shfl(ej, k + 3, 32);
            float x0 = y1[(size_t)(v0 & 0xFFFFF) * HID + lane];
            float x1 = y1[(size_t)(v1 & 0xFFFFF) * HID + lane];
            float x2 = y1[(size_t)(v2 & 0xFFFFF) * HID + lane];
            float x3 = y1[(size_t)(v3 & 0xFFFFF) * HID + lane];
            atomicAdd(&acc[(v0 >> 20) * HID + lane], x0);
            atomicAdd(&acc[(v1 >> 20) * HID + lane], x1);
            atomicAdd(&acc[(v2 >> 20) * HID + lane], x2);
            atomicAdd(&acc[(v3 >> 20) * HID + lane], x3);
        }
        for (; k < m; ++k) {
            unsigned int v = __shfl(ej, k, 32);
            float xv = y1[(size_t)(v & 0xFFFFF) * HID + lane];
            atomicAdd(&acc[(v >> 20) * HID + lane], xv);
        }
    }
    __syncthreads();
    float bias = b1[lane], w2 = W2[lane];
    for (int vl = grp; vl < BNODES; vl += 8) {
        int v = b * BNODES + vl;
        if (v >= N_NODES) break;          // uniform per group
        float a = acc[vl * HID + lane] + y1[(size_t)v * HID + lane];  // + self loop
        float di = dinv[v];
        float h = fmaxf(fmaf(di, a, bias), 0.f);
        out_h[(size_t)v * HID + lane] = h;
        float p = h * w2;
        #pragma unroll
        for (int off = 16; off > 0; off >>= 1) p += __shfl_xor(p, off);
        if (lane == 0) y2[v] = di * p;
    }
}

// Layer-2 aggregation per bucket: scalar LDS accumulator
__launch_bounds__(256)
__global__ void k_gather2(const unsigned int* __restrict__ ebuf, const int* __restrict__ boff,
                          const int* __restrict__ bcnt, const float* __restrict__ y2,
                          const float* __restrict__ dinv, const float* __restrict__ b2,
                          float* __restrict__ scores) {
    __shared__ float acc[BNODES];
    int t = threadIdx.x;
    if (t < BNODES) acc[t] = 0.f;
    __syncthreads();
    int b = blockIdx.x;
    int s0 = boff[b], n = bcnt[b];
    for (int j = t; j < n; j += 256) {
        unsigned int v = ebuf[s0 + j];
        atomicAdd(&acc[v >> 20], y2[v & 0xFFFFF]);
    }
    __syncthreads();
    int v = b * BNODES + t;
    if (t < BNODES && v < N_NODES)
        scores[v] = dinv[v] * (acc[t] + y2[v]) + b2[0];
}

extern "C" void kernel_launch(void* const* d_in, const int* in_sizes, int n_in,
                              void* d_out, int out_size, void* d_ws, size_t ws_size,
                              hipStream_t stream) {
    const float* x  = (const float*)d_in[0];
    const int* ei   = (const int*)d_in[1];
    const float* W1 = (const float*)d_in[2];
    const float* b1 = (const float*)d_in[3];
    const float* W2 = (const float*)d_in[4];
    const float* b2 = (const float*)d_in[5];

    const int* src = ei;             // edge_index[0]
    const int* dst = ei + N_EDGES;   // edge_index[1]

    int* bcnt = (int*)d_ws;                         // NBP
    int* boff = bcnt + NBP;                         // NBP
    int* gcur = boff + NBP;                         // NBP
    unsigned int* ebuf = (unsigned int*)(gcur + NBP);  // E
    float* dinv = (float*)(ebuf + N_EDGES);         // N
    float* y1   = dinv + N_NODES;                   // N*HID
    float* y2   = y1 + (size_t)N_NODES * HID;       // N

    float* out_h = (float*)d_out;                   // N*HID
    float* out_s = out_h + (size_t)N_NODES * HID;   // N

    k_zeroB <<<1, NBP, 0, stream>>>(bcnt);
    k_bhist <<<512, 256, 0, stream>>>(dst, bcnt);
    k_bscan <<<1, 256, 0, stream>>>(bcnt, boff, gcur);
    k_bfill <<<NFILL, 256, 0, stream>>>(src, dst, gcur, ebuf);
    k_bcount<<<NBUK, 256, 0, stream>>>(ebuf, boff, bcnt, dinv);
    k_gemm1 <<<(N_NODES + 7) / 8, 256, 0, stream>>>(x, W1, dinv, y1);
    k_gather1<<<NBUK, 256, 0, stream>>>(ebuf, boff, bcnt, y1, dinv, b1, W2, out_h, y2);
    k_gather2<<<NBUK, 256, 0, stream>>>(ebuf, boff, bcnt, y2, dinv, b2, out_s);
}

// Round 4
// 777.541 us; speedup vs baseline: 1.1109x; 1.1109x over previous
//
#include <hip/hip_runtime.h>

#define N_NODES 100000
#define N_EDGES 3200000
#define DIM 128
#define HID 32

#define BSH 6                                   // bucket = dst >> 6
#define BNODES (1 << BSH)                       // 64 nodes per bucket
#define NBUK ((N_NODES + BNODES - 1) >> BSH)    // 1563
#define NBP 2048                                // padded (pow2) bucket count
#define FCHUNK 8192                             // edges per partition block
#define NFILL ((N_EDGES + FCHUNK - 1) / FCHUNK) // 391
#define G1_THREADS 512
#define G1_GROUPS (G1_THREADS / 32)             // 16

// Workspace: bcnt[NBP] boff[NBP] gcur[NBP] ebuf[E] dinv[N] y1[N*HID] y2[N]

__global__ void k_zeroB(int* __restrict__ bcnt) {
    int i = blockIdx.x * blockDim.x + threadIdx.x;
    if (i < NBP) bcnt[i] = 0;
}

// global bucket histogram via per-block LDS histogram
__launch_bounds__(256)
__global__ void k_bhist(const int* __restrict__ dst, int* __restrict__ bcnt) {
    __shared__ int h[NBP];
    for (int i = threadIdx.x; i < NBP; i += 256) h[i] = 0;
    __syncthreads();
    int stride = gridDim.x * blockDim.x;
    for (int e = blockIdx.x * blockDim.x + threadIdx.x; e < N_EDGES; e += stride)
        atomicAdd(&h[dst[e] >> BSH], 1);
    __syncthreads();
    for (int i = threadIdx.x; i < NBP; i += 256)
        if (h[i]) atomicAdd(&bcnt[i], h[i]);
}

// single block: exclusive scan of bcnt[NBP] -> boff, working copy -> gcur
__global__ void k_bscan(const int* __restrict__ bcnt, int* __restrict__ boff,
                        int* __restrict__ gcur) {
    __shared__ int s[256];
    int t = threadIdx.x;
    int c[8]; int sum = 0;
    #pragma unroll
    for (int k = 0; k < 8; ++k) { c[k] = bcnt[t * 8 + k]; sum += c[k]; }
    s[t] = sum; __syncthreads();
    for (int d = 1; d < 256; d <<= 1) {
        int add = (t >= d) ? s[t - d] : 0;
        __syncthreads();
        s[t] += add;
        __syncthreads();
    }
    int excl = s[t] - sum;
    #pragma unroll
    for (int k = 0; k < 8; ++k) {
        boff[t * 8 + k] = excl;
        gcur[t * 8 + k] = excl;
        excl += c[k];
    }
}

// Partition edges into bucket-ordered ebuf with LDS staging + coalesced flush.
// packed edge = (dst & 63) << 20 | src   (src < 2^17)
__launch_bounds__(256)
__global__ void k_bfill(const int* __restrict__ src, const int* __restrict__ dst,
                        int* __restrict__ gcur, unsigned int* __restrict__ ebuf) {
    __shared__ int cntA[NBP];               // pass-1 counts, then reused as pass-2 cursors
    __shared__ int offA[NBP];               // exclusive offsets within chunk
    __shared__ int baseG[NBP];              // reserved global base per bucket
    __shared__ int ssum[256];
    __shared__ unsigned int stage[FCHUNK];  // 32 KB
    int t = threadIdx.x;
    int e0 = blockIdx.x * FCHUNK;
    int eN = min(e0 + FCHUNK, N_EDGES) - e0;
    for (int i = t; i < NBP; i += 256) cntA[i] = 0;
    __syncthreads();
    // pass 1: count buckets in this chunk
    for (int i = t; i < eN; i += 256)
        atomicAdd(&cntA[dst[e0 + i] >> BSH], 1);
    __syncthreads();
    // LDS exclusive scan cntA -> offA (8 elems/thread)
    {
        int c[8]; int sum = 0;
        #pragma unroll
        for (int k = 0; k < 8; ++k) { c[k] = cntA[t * 8 + k]; sum += c[k]; }
        ssum[t] = sum; __syncthreads();
        for (int d = 1; d < 256; d <<= 1) {
            int add = (t >= d) ? ssum[t - d] : 0;
            __syncthreads();
            ssum[t] += add;
            __syncthreads();
        }
        int excl = ssum[t] - sum;
        #pragma unroll
        for (int k = 0; k < 8; ++k) { offA[t * 8 + k] = excl; excl += c[k]; }
    }
    __syncthreads();
    // reserve global space per bucket (counts are final)
    for (int b = t; b < NBP; b += 256)
        if (cntA[b] > 0) baseG[b] = atomicAdd(&gcur[b], cntA[b]);
    __syncthreads();
    // reuse cntA as pass-2 cursors
    for (int i = t; i < NBP; i += 256) cntA[i] = 0;
    __syncthreads();
    // pass 2: re-read edges, place packed into LDS stage at bucket-local position
    for (int i = t; i < eN; i += 256) {
        int d = dst[e0 + i];
        int b = d >> BSH;
        unsigned int packed = ((unsigned int)(d & (BNODES - 1)) << 20)
                            | (unsigned int)src[e0 + i];
        int pos = offA[b] + atomicAdd(&cntA[b], 1);
        stage[pos] = packed;
    }
    __syncthreads();
    // coalesced flush: stage index i -> bucket via binary search (largest b: offA[b] <= i)
    for (int i = t; i < eN; i += 256) {
        int lo = 0, hi = NBP - 1;
        while (lo < hi) {
            int mid = (lo + hi + 1) >> 1;
            if (offA[mid] <= i) lo = mid; else hi = mid - 1;
        }
        ebuf[baseG[lo] + (i - offA[lo])] = stage[i];
    }
}

// per-bucket node in-degrees -> dinv = rsqrt(deg+1)
__launch_bounds__(256)
__global__ void k_bcount(const unsigned int* __restrict__ ebuf, const int* __restrict__ boff,
                         const int* __restrict__ bcnt, float* __restrict__ dinv) {
    __shared__ int cnt[BNODES];
    int t = threadIdx.x;
    if (t < BNODES) cnt[t] = 0;
    __syncthreads();
    int b = blockIdx.x;
    int s0 = boff[b], n = bcnt[b];
    for (int j = t; j < n; j += 256)
        atomicAdd(&cnt[ebuf[s0 + j] >> 20], 1);
    __syncthreads();
    int v = b * BNODES + t;
    if (t < BNODES && v < N_NODES) dinv[v] = rsqrtf((float)(cnt[t] + 1));
}

// y1[v][c] = dinv[v] * sum_k x[v][k] * W1[k][c]; 8 nodes x 32 cols per block
__launch_bounds__(256)
__global__ void k_gemm1(const float* __restrict__ x, const float* __restrict__ W1,
                        const float* __restrict__ dinv, float* __restrict__ y1) {
    __shared__ float Wl[DIM * HID];
    for (int i = threadIdx.x; i < DIM * HID; i += 256) Wl[i] = W1[i];
    __syncthreads();
    int node = blockIdx.x * 8 + (threadIdx.x >> 5);
    int col = threadIdx.x & 31;
    if (node >= N_NODES) return;
    const float4* x4 = (const float4*)(x + (size_t)node * DIM);
    float acc = 0.0f;
    #pragma unroll
    for (int k4 = 0; k4 < DIM / 4; ++k4) {
        float4 v = x4[k4];
        int k = k4 * 4;
        acc = fmaf(v.x, Wl[(k + 0) * HID + col], acc);
        acc = fmaf(v.y, Wl[(k + 1) * HID + col], acc);
        acc = fmaf(v.z, Wl[(k + 2) * HID + col], acc);
        acc = fmaf(v.w, Wl[(k + 3) * HID + col], acc);
    }
    y1[(size_t)node * HID + col] = dinv[node] * acc;
}

// Layer-1 aggregation per bucket: LDS accumulator [64 nodes][32 cols], lane = col.
// 512 threads = 16 groups; 8-deep gather pipeline.
// Fused epilogue: h = relu(dinv*(acc+self)+b1) -> out_h; y2 = dinv*(h.W2)
__launch_bounds__(G1_THREADS)
__global__ void k_gather1(const unsigned int* __restrict__ ebuf, const int* __restrict__ boff,
                          const int* __restrict__ bcnt, const float* __restrict__ y1,
                          const float* __restrict__ dinv, const float* __restrict__ b1,
                          const float* __restrict__ W2, float* __restrict__ out_h,
                          float* __restrict__ y2) {
    __shared__ float acc[BNODES * HID];   // 8 KB
    int t = threadIdx.x;
    int lane = t & 31;
    int grp = t >> 5;                     // 0..15
    for (int i = t; i < BNODES * HID; i += G1_THREADS) acc[i] = 0.f;
    __syncthreads();
    int b = blockIdx.x;
    int s0 = boff[b], n = bcnt[b];
    for (int base = grp * 32; base < n; base += G1_GROUPS * 32) {
        int m = min(32, n - base);
        unsigned int ej = 0;
        if (lane < m) ej = ebuf[s0 + base + lane];   // coalesced slab
        int k = 0;
        for (; k + 8 <= m; k += 8) {                 // 8 independent gathers in flight
            unsigned int v0 = __shfl(ej, k + 0, 32);
            unsigned int v1 = __shfl(ej, k + 1, 32);
            unsigned int v2 = __shfl(ej, k + 2, 32);
            unsigned int v3 = __shfl(ej, k + 3, 32);
            unsigned int v4 = __shfl(ej, k + 4, 32);
            unsigned int v5 = __shfl(ej, k + 5, 32);
            unsigned int v6 = __shfl(ej, k + 6, 32);
            unsigned int v7 = __shfl(ej, k + 7, 32);
            float x0 = y1[(size_t)(v0 & 0xFFFFF) * HID + lane];
            float x1 = y1[(size_t)(v1 & 0xFFFFF) * HID + lane];
            float x2 = y1[(size_t)(v2 & 0xFFFFF) * HID + lane];
            float x3 = y1[(size_t)(v3 & 0xFFFFF) * HID + lane];
            float x4 = y1[(size_t)(v4 & 0xFFFFF) * HID + lane];
            float x5 = y1[(size_t)(v5 & 0xFFFFF) * HID + lane];
            float x6 = y1[(size_t)(v6 & 0xFFFFF) * HID + lane];
            float x7 = y1[(size_t)(v7 & 0xFFFFF) * HID + lane];
            atomicAdd(&acc[(v0 >> 20) * HID + lane], x0);
            atomicAdd(&acc[(v1 >> 20) * HID + lane], x1);
            atomicAdd(&acc[(v2 >> 20) * HID + lane], x2);
            atomicAdd(&acc[(v3 >> 20) * HID + lane], x3);
            atomicAdd(&acc[(v4 >> 20) * HID + lane], x4);
            atomicAdd(&acc[(v5 >> 20) * HID + lane], x5);
            atomicAdd(&acc[(v6 >> 20) * HID + lane], x6);
            atomicAdd(&acc[(v7 >> 20) * HID + lane], x7);
        }
        for (; k < m; ++k) {
            unsigned int v = __shfl(ej, k, 32);
            float xv = y1[(size_t)(v & 0xFFFFF) * HID + lane];
            atomicAdd(&acc[(v >> 20) * HID + lane], xv);
        }
    }
    __syncthreads();
    float bias = b1[lane], w2 = W2[lane];
    for (int vl = grp; vl < BNODES; vl += G1_GROUPS) {   // 4 iterations
        int v = b * BNODES + vl;
        if (v >= N_NODES) break;          // uniform per group
        float a = acc[vl * HID + lane] + y1[(size_t)v * HID + lane];  // + self loop
        float di = dinv[v];
        float h = fmaxf(fmaf(di, a, bias), 0.f);
        out_h[(size_t)v * HID + lane] = h;
        float p = h * w2;
        #pragma unroll
        for (int off = 16; off > 0; off >>= 1) p += __shfl_xor(p, off);
        if (lane == 0) y2[v] = di * p;
    }
}

// Layer-2 aggregation per bucket: scalar LDS accumulator
__launch_bounds__(256)
__global__ void k_gather2(const unsigned int* __restrict__ ebuf, const int* __restrict__ boff,
                          const int* __restrict__ bcnt, const float* __restrict__ y2,
                          const float* __restrict__ dinv, const float* __restrict__ b2,
                          float* __restrict__ scores) {
    __shared__ float acc[BNODES];
    int t = threadIdx.x;
    if (t < BNODES) acc[t] = 0.f;
    __syncthreads();
    int b = blockIdx.x;
    int s0 = boff[b], n = bcnt[b];
    for (int j = t; j < n; j += 256) {
        unsigned int v = ebuf[s0 + j];
        atomicAdd(&acc[v >> 20], y2[v & 0xFFFFF]);
    }
    __syncthreads();
    int v = b * BNODES + t;
    if (t < BNODES && v < N_NODES)
        scores[v] = dinv[v] * (acc[t] + y2[v]) + b2[0];
}

extern "C" void kernel_launch(void* const* d_in, const int* in_sizes, int n_in,
                              void* d_out, int out_size, void* d_ws, size_t ws_size,
                              hipStream_t stream) {
    const float* x  = (const float*)d_in[0];
    const int* ei   = (const int*)d_in[1];
    const float* W1 = (const float*)d_in[2];
    const float* b1 = (const float*)d_in[3];
    const float* W2 = (const float*)d_in[4];
    const float* b2 = (const float*)d_in[5];

    const int* src = ei;             // edge_index[0]
    const int* dst = ei + N_EDGES;   // edge_index[1]

    int* bcnt = (int*)d_ws;                         // NBP
    int* boff = bcnt + NBP;                         // NBP
    int* gcur = boff + NBP;                         // NBP
    unsigned int* ebuf = (unsigned int*)(gcur + NBP);  // E
    float* dinv = (float*)(ebuf + N_EDGES);         // N
    float* y1   = dinv + N_NODES;                   // N*HID
    float* y2   = y1 + (size_t)N_NODES * HID;       // N

    float* out_h = (float*)d_out;                   // N*HID
    float* out_s = out_h + (size_t)N_NODES * HID;   // N

    k_zeroB <<<NBP / 256, 256, 0, stream>>>(bcnt);
    k_bhist <<<512, 256, 0, stream>>>(dst, bcnt);
    k_bscan <<<1, 256, 0, stream>>>(bcnt, boff, gcur);
    k_bfill <<<NFILL, 256, 0, stream>>>(src, dst, gcur, ebuf);
    k_bcount<<<NBUK, 256, 0, stream>>>(ebuf, boff, bcnt, dinv);
    k_gemm1 <<<(N_NODES + 7) / 8, 256, 0, stream>>>(x, W1, dinv, y1);
    k_gather1<<<NBUK, G1_THREADS, 0, stream>>>(ebuf, boff, bcnt, y1, dinv, b1, W2, out_h, y2);
    k_gather2<<<NBUK, 256, 0, stream>>>(ebuf, boff, bcnt, y2, dinv, b2, out_s);
}

// Round 5
// 759.897 us; speedup vs baseline: 1.1367x; 1.0232x over previous
//
#include <hip/hip_runtime.h>

#define N_NODES 100000
#define N_EDGES 3200000
#define DIM 128
#define HID 32

#define BSH 6                                   // bucket = dst >> 6
#define BNODES (1 << BSH)                       // 64 nodes per bucket
#define NBUK ((N_NODES + BNODES - 1) >> BSH)    // 1563
#define NBP 2048                                // padded (pow2) bucket count
#define FCHUNK 8192                             // edges per partition block
#define NFILL ((N_EDGES + FCHUNK - 1) / FCHUNK) // 391
#define G1_THREADS 512                          // 8 waves per bucket-block

// Workspace: bcnt[NBP] boff[NBP] gcur[NBP] ebuf[E] dinv[N] y1[N*HID] y2[N]

__global__ void k_zeroB(int* __restrict__ bcnt) {
    int i = blockIdx.x * blockDim.x + threadIdx.x;
    if (i < NBP) bcnt[i] = 0;
}

// global bucket histogram via per-block LDS histogram
__launch_bounds__(256)
__global__ void k_bhist(const int* __restrict__ dst, int* __restrict__ bcnt) {
    __shared__ int h[NBP];
    for (int i = threadIdx.x; i < NBP; i += 256) h[i] = 0;
    __syncthreads();
    int stride = gridDim.x * blockDim.x;
    for (int e = blockIdx.x * blockDim.x + threadIdx.x; e < N_EDGES; e += stride)
        atomicAdd(&h[dst[e] >> BSH], 1);
    __syncthreads();
    for (int i = threadIdx.x; i < NBP; i += 256)
        if (h[i]) atomicAdd(&bcnt[i], h[i]);
}

// single block: exclusive scan of bcnt[NBP] -> boff, working copy -> gcur
__global__ void k_bscan(const int* __restrict__ bcnt, int* __restrict__ boff,
                        int* __restrict__ gcur) {
    __shared__ int s[256];
    int t = threadIdx.x;
    int c[8]; int sum = 0;
    #pragma unroll
    for (int k = 0; k < 8; ++k) { c[k] = bcnt[t * 8 + k]; sum += c[k]; }
    s[t] = sum; __syncthreads();
    for (int d = 1; d < 256; d <<= 1) {
        int add = (t >= d) ? s[t - d] : 0;
        __syncthreads();
        s[t] += add;
        __syncthreads();
    }
    int excl = s[t] - sum;
    #pragma unroll
    for (int k = 0; k < 8; ++k) {
        boff[t * 8 + k] = excl;
        gcur[t * 8 + k] = excl;
        excl += c[k];
    }
}

// Partition edges into bucket-ordered ebuf with LDS staging + coalesced flush.
// packed edge = (dst & 63) << 20 | src   (src < 2^17)
__launch_bounds__(256)
__global__ void k_bfill(const int* __restrict__ src, const int* __restrict__ dst,
                        int* __restrict__ gcur, unsigned int* __restrict__ ebuf) {
    __shared__ int cntA[NBP];               // pass-1 counts, then reused as pass-2 cursors
    __shared__ int offA[NBP];               // exclusive offsets within chunk
    __shared__ int baseG[NBP];              // reserved global base per bucket
    __shared__ int ssum[256];
    __shared__ unsigned int stage[FCHUNK];  // 32 KB
    int t = threadIdx.x;
    int e0 = blockIdx.x * FCHUNK;
    int eN = min(e0 + FCHUNK, N_EDGES) - e0;
    for (int i = t; i < NBP; i += 256) cntA[i] = 0;
    __syncthreads();
    // pass 1: count buckets in this chunk
    for (int i = t; i < eN; i += 256)
        atomicAdd(&cntA[dst[e0 + i] >> BSH], 1);
    __syncthreads();
    // LDS exclusive scan cntA -> offA (8 elems/thread)
    {
        int c[8]; int sum = 0;
        #pragma unroll
        for (int k = 0; k < 8; ++k) { c[k] = cntA[t * 8 + k]; sum += c[k]; }
        ssum[t] = sum; __syncthreads();
        for (int d = 1; d < 256; d <<= 1) {
            int add = (t >= d) ? ssum[t - d] : 0;
            __syncthreads();
            ssum[t] += add;
            __syncthreads();
        }
        int excl = ssum[t] - sum;
        #pragma unroll
        for (int k = 0; k < 8; ++k) { offA[t * 8 + k] = excl; excl += c[k]; }
    }
    __syncthreads();
    // reserve global space per bucket (counts are final)
    for (int b = t; b < NBP; b += 256)
        if (cntA[b] > 0) baseG[b] = atomicAdd(&gcur[b], cntA[b]);
    __syncthreads();
    // reuse cntA as pass-2 cursors
    for (int i = t; i < NBP; i += 256) cntA[i] = 0;
    __syncthreads();
    // pass 2: re-read edges, place packed into LDS stage at bucket-local position
    for (int i = t; i < eN; i += 256) {
        int d = dst[e0 + i];
        int b = d >> BSH;
        unsigned int packed = ((unsigned int)(d & (BNODES - 1)) << 20)
                            | (unsigned int)src[e0 + i];
        int pos = offA[b] + atomicAdd(&cntA[b], 1);
        stage[pos] = packed;
    }
    __syncthreads();
    // coalesced flush: stage index i -> bucket via binary search (largest b: offA[b] <= i)
    for (int i = t; i < eN; i += 256) {
        int lo = 0, hi = NBP - 1;
        while (lo < hi) {
            int mid = (lo + hi + 1) >> 1;
            if (offA[mid] <= i) lo = mid; else hi = mid - 1;
        }
        ebuf[baseG[lo] + (i - offA[lo])] = stage[i];
    }
}

// per-bucket node in-degrees -> dinv = rsqrt(deg+1)
__launch_bounds__(256)
__global__ void k_bcount(const unsigned int* __restrict__ ebuf, const int* __restrict__ boff,
                         const int* __restrict__ bcnt, float* __restrict__ dinv) {
    __shared__ int cnt[BNODES];
    int t = threadIdx.x;
    if (t < BNODES) cnt[t] = 0;
    __syncthreads();
    int b = blockIdx.x;
    int s0 = boff[b], n = bcnt[b];
    for (int j = t; j < n; j += 256)
        atomicAdd(&cnt[ebuf[s0 + j] >> 20], 1);
    __syncthreads();
    int v = b * BNODES + t;
    if (t < BNODES && v < N_NODES) dinv[v] = rsqrtf((float)(cnt[t] + 1));
}

// y1[v][c] = dinv[v] * sum_k x[v][k] * W1[k][c]; 8 nodes x 32 cols per block
__launch_bounds__(256)
__global__ void k_gemm1(const float* __restrict__ x, const float* __restrict__ W1,
                        const float* __restrict__ dinv, float* __restrict__ y1) {
    __shared__ float Wl[DIM * HID];
    for (int i = threadIdx.x; i < DIM * HID; i += 256) Wl[i] = W1[i];
    __syncthreads();
    int node = blockIdx.x * 8 + (threadIdx.x >> 5);
    int col = threadIdx.x & 31;
    if (node >= N_NODES) return;
    const float4* x4 = (const float4*)(x + (size_t)node * DIM);
    float acc = 0.0f;
    #pragma unroll
    for (int k4 = 0; k4 < DIM / 4; ++k4) {
        float4 v = x4[k4];
        int k = k4 * 4;
        acc = fmaf(v.x, Wl[(k + 0) * HID + col], acc);
        acc = fmaf(v.y, Wl[(k + 1) * HID + col], acc);
        acc = fmaf(v.z, Wl[(k + 2) * HID + col], acc);
        acc = fmaf(v.w, Wl[(k + 3) * HID + col], acc);
    }
    y1[(size_t)node * HID + col] = dinv[node] * acc;
}

// Layer-1 aggregation per bucket. Lane = (edge, col-pair): 64 lanes = 4 edges x 16 float2.
// One global_load_dwordx2 gathers 4 edges' rows; 8-deep batch = 32 edges in flight/wave.
// sched_barrier(0) fences keep {edge loads} / {row gathers} / {LDS atomics} grouped so the
// scheduler can't sink loads to uses (round-4 failure mode: VGPR=20, MLP=1).
__launch_bounds__(G1_THREADS)
__global__ void k_gather1(const unsigned int* __restrict__ ebuf, const int* __restrict__ boff,
                          const int* __restrict__ bcnt, const float* __restrict__ y1,
                          const float* __restrict__ dinv, const float* __restrict__ b1,
                          const float* __restrict__ W2, float* __restrict__ out_h,
                          float* __restrict__ y2) {
    __shared__ float acc[BNODES * HID];   // 8 KB
    int t = threadIdx.x;
    for (int i = t; i < BNODES * HID; i += G1_THREADS) acc[i] = 0.f;
    __syncthreads();
    int b = blockIdx.x;
    int s0 = boff[b], n = bcnt[b];
    int wave = t >> 6;                    // 0..7
    int lane = t & 63;
    int esub = lane >> 4;                 // which of 4 edges this lane serves
    int cp = (lane & 15) * 2;             // col pair base (0,2,..,30)

    for (int base = wave * 32; base < n; base += 8 * 32) {   // 32 edges per wave per iter
        unsigned int pp[8];
        float2 vv[8];
        #pragma unroll
        for (int k = 0; k < 8; ++k) {                        // edge-word loads (L1-merged)
            int idx = base + 4 * k + esub;
            pp[k] = ebuf[s0 + ((idx < n) ? idx : 0)];
        }
        __builtin_amdgcn_sched_barrier(0);
        #pragma unroll
        for (int k = 0; k < 8; ++k) {                        // 8 gathers, 4 edges each
            vv[k] = *(const float2*)(y1 + (size_t)(pp[k] & 0xFFFFF) * HID + cp);
        }
        __builtin_amdgcn_sched_barrier(0);
        #pragma unroll
        for (int k = 0; k < 8; ++k) {
            int idx = base + 4 * k + esub;
            if (idx < n) {
                float* a = &acc[(pp[k] >> 20) * HID + cp];
                atomicAdd(a + 0, vv[k].x);
                atomicAdd(a + 1, vv[k].y);
            }
        }
        __builtin_amdgcn_sched_barrier(0);
    }
    __syncthreads();
    // Fused epilogue: h = relu(dinv*(acc+self)+b1) -> out_h; y2 = dinv*(h.W2)
    int lane32 = t & 31;
    int grp = t >> 5;                     // 0..15
    float bias = b1[lane32], w2 = W2[lane32];
    for (int vl = grp; vl < BNODES; vl += G1_THREADS / 32) {
        int v = b * BNODES + vl;
        if (v >= N_NODES) break;          // uniform per group
        float a = acc[vl * HID + lane32] + y1[(size_t)v * HID + lane32];  // + self loop
        float di = dinv[v];
        float h = fmaxf(fmaf(di, a, bias), 0.f);
        out_h[(size_t)v * HID + lane32] = h;
        float p = h * w2;
        #pragma unroll
        for (int off = 16; off > 0; off >>= 1) p += __shfl_xor(p, off);
        if (lane32 == 0) y2[v] = di * p;
    }
}

// Layer-2 aggregation per bucket: scalar LDS accumulator (64 edges per vmem instr via SIMT)
__launch_bounds__(256)
__global__ void k_gather2(const unsigned int* __restrict__ ebuf, const int* __restrict__ boff,
                          const int* __restrict__ bcnt, const float* __restrict__ y2,
                          const float* __restrict__ dinv, const float* __restrict__ b2,
                          float* __restrict__ scores) {
    __shared__ float acc[BNODES];
    int t = threadIdx.x;
    if (t < BNODES) acc[t] = 0.f;
    __syncthreads();
    int b = blockIdx.x;
    int s0 = boff[b], n = bcnt[b];
    for (int j = t; j < n; j += 256) {
        unsigned int v = ebuf[s0 + j];
        atomicAdd(&acc[v >> 20], y2[v & 0xFFFFF]);
    }
    __syncthreads();
    int v = b * BNODES + t;
    if (t < BNODES && v < N_NODES)
        scores[v] = dinv[v] * (acc[t] + y2[v]) + b2[0];
}

extern "C" void kernel_launch(void* const* d_in, const int* in_sizes, int n_in,
                              void* d_out, int out_size, void* d_ws, size_t ws_size,
                              hipStream_t stream) {
    const float* x  = (const float*)d_in[0];
    const int* ei   = (const int*)d_in[1];
    const float* W1 = (const float*)d_in[2];
    const float* b1 = (const float*)d_in[3];
    const float* W2 = (const float*)d_in[4];
    const float* b2 = (const float*)d_in[5];

    const int* src = ei;             // edge_index[0]
    const int* dst = ei + N_EDGES;   // edge_index[1]

    int* bcnt = (int*)d_ws;                         // NBP
    int* boff = bcnt + NBP;                         // NBP
    int* gcur = boff + NBP;                         // NBP
    unsigned int* ebuf = (unsigned int*)(gcur + NBP);  // E
    float* dinv = (float*)(ebuf + N_EDGES);         // N
    float* y1   = dinv + N_NODES;                   // N*HID
    float* y2   = y1 + (size_t)N_NODES * HID;       // N

    float* out_h = (float*)d_out;                   // N*HID
    float* out_s = out_h + (size_t)N_NODES * HID;   // N

    k_zeroB <<<NBP / 256, 256, 0, stream>>>(bcnt);
    k_bhist <<<512, 256, 0, stream>>>(dst, bcnt);
    k_bscan <<<1, 256, 0, stream>>>(bcnt, boff, gcur);
    k_bfill <<<NFILL, 256, 0, stream>>>(src, dst, gcur, ebuf);
    k_bcount<<<NBUK, 256, 0, stream>>>(ebuf, boff, bcnt, dinv);
    k_gemm1 <<<(N_NODES + 7) / 8, 256, 0, stream>>>(x, W1, dinv, y1);
    k_gather1<<<NBUK, G1_THREADS, 0, stream>>>(ebuf, boff, bcnt, y1, dinv, b1, W2, out_h, y2);
    k_gather2<<<NBUK, 256, 0, stream>>>(ebuf, boff, bcnt, y2, dinv, b2, out_s);
}

// Round 6
// 265.842 us; speedup vs baseline: 3.2491x; 2.8585x over previous
//
#include <hip/hip_runtime.h>

#define N_NODES 100000
#define N_EDGES 3200000
#define DIM 128
#define HID 32

#define BSH 6                                   // bucket = dst >> 6
#define BNODES (1 << BSH)                       // 64 nodes per bucket
#define NBUK ((N_NODES + BNODES - 1) >> BSH)    // 1563
#define NBP 2048                                // padded (pow2) bucket count
#define FCHUNK 8192                             // edges per partition block
#define NFILL ((N_EDGES + FCHUNK - 1) / FCHUNK) // 391
#define SLAB 4096                               // per-bucket sort capacity (mean 2048, 45 sigma)

// Workspace: bcnt[NBP] boff[NBP] gcur[NBP] ebuf[E] rowptr[NBUK*64+4] dinv[N] y1[N*HID] y2[N]

__global__ void k_zeroB(int* __restrict__ bcnt) {
    int i = blockIdx.x * blockDim.x + threadIdx.x;
    if (i < NBP) bcnt[i] = 0;
}

// global bucket histogram via per-block LDS histogram
__launch_bounds__(256)
__global__ void k_bhist(const int* __restrict__ dst, int* __restrict__ bcnt) {
    __shared__ int h[NBP];
    for (int i = threadIdx.x; i < NBP; i += 256) h[i] = 0;
    __syncthreads();
    int stride = gridDim.x * blockDim.x;
    for (int e = blockIdx.x * blockDim.x + threadIdx.x; e < N_EDGES; e += stride)
        atomicAdd(&h[dst[e] >> BSH], 1);
    __syncthreads();
    for (int i = threadIdx.x; i < NBP; i += 256)
        if (h[i]) atomicAdd(&bcnt[i], h[i]);
}

// single block: exclusive scan of bcnt[NBP] -> boff, working copy -> gcur
__global__ void k_bscan(const int* __restrict__ bcnt, int* __restrict__ boff,
                        int* __restrict__ gcur) {
    __shared__ int s[256];
    int t = threadIdx.x;
    int c[8]; int sum = 0;
    #pragma unroll
    for (int k = 0; k < 8; ++k) { c[k] = bcnt[t * 8 + k]; sum += c[k]; }
    s[t] = sum; __syncthreads();
    for (int d = 1; d < 256; d <<= 1) {
        int add = (t >= d) ? s[t - d] : 0;
        __syncthreads();
        s[t] += add;
        __syncthreads();
    }
    int excl = s[t] - sum;
    #pragma unroll
    for (int k = 0; k < 8; ++k) {
        boff[t * 8 + k] = excl;
        gcur[t * 8 + k] = excl;
        excl += c[k];
    }
}

// Partition edges into bucket-ordered ebuf with LDS staging + coalesced flush.
// packed edge = (dst & 63) << 20 | src   (src < 2^17)
__launch_bounds__(256)
__global__ void k_bfill(const int* __restrict__ src, const int* __restrict__ dst,
                        int* __restrict__ gcur, unsigned int* __restrict__ ebuf) {
    __shared__ int cntA[NBP];               // pass-1 counts, then reused as pass-2 cursors
    __shared__ int offA[NBP];               // exclusive offsets within chunk
    __shared__ int baseG[NBP];              // reserved global base per bucket
    __shared__ int ssum[256];
    __shared__ unsigned int stage[FCHUNK];  // 32 KB
    int t = threadIdx.x;
    int e0 = blockIdx.x * FCHUNK;
    int eN = min(e0 + FCHUNK, N_EDGES) - e0;
    for (int i = t; i < NBP; i += 256) cntA[i] = 0;
    __syncthreads();
    for (int i = t; i < eN; i += 256)
        atomicAdd(&cntA[dst[e0 + i] >> BSH], 1);
    __syncthreads();
    {
        int c[8]; int sum = 0;
        #pragma unroll
        for (int k = 0; k < 8; ++k) { c[k] = cntA[t * 8 + k]; sum += c[k]; }
        ssum[t] = sum; __syncthreads();
        for (int d = 1; d < 256; d <<= 1) {
            int add = (t >= d) ? ssum[t - d] : 0;
            __syncthreads();
            ssum[t] += add;
            __syncthreads();
        }
        int excl = ssum[t] - sum;
        #pragma unroll
        for (int k = 0; k < 8; ++k) { offA[t * 8 + k] = excl; excl += c[k]; }
    }
    __syncthreads();
    for (int b = t; b < NBP; b += 256)
        if (cntA[b] > 0) baseG[b] = atomicAdd(&gcur[b], cntA[b]);
    __syncthreads();
    for (int i = t; i < NBP; i += 256) cntA[i] = 0;
    __syncthreads();
    for (int i = t; i < eN; i += 256) {
        int d = dst[e0 + i];
        int b = d >> BSH;
        unsigned int packed = ((unsigned int)(d & (BNODES - 1)) << 20)
                            | (unsigned int)src[e0 + i];
        int pos = offA[b] + atomicAdd(&cntA[b], 1);
        stage[pos] = packed;
    }
    __syncthreads();
    for (int i = t; i < eN; i += 256) {
        int lo = 0, hi = NBP - 1;
        while (lo < hi) {
            int mid = (lo + hi + 1) >> 1;
            if (offA[mid] <= i) lo = mid; else hi = mid - 1;
        }
        ebuf[baseG[lo] + (i - offA[lo])] = stage[i];
    }
}

// Per-bucket LDS counting sort by dlocal -> ebuf globally dst-sorted (CSR order).
// Also emits rowptr[v] (global row starts) and dinv[v] = rsqrt(deg+1).
__launch_bounds__(256)
__global__ void k_sort(unsigned int* __restrict__ ebuf, const int* __restrict__ boff,
                       const int* __restrict__ bcnt, int* __restrict__ rowptr,
                       float* __restrict__ dinv) {
    __shared__ unsigned int slab[SLAB];    // 16 KB
    __shared__ unsigned int slab2[SLAB];   // 16 KB
    __shared__ int hist[BNODES];
    __shared__ int scanx[BNODES];
    __shared__ int cur[BNODES];
    int t = threadIdx.x;
    int b = blockIdx.x;
    int s0 = boff[b];
    int n = min(bcnt[b], SLAB);
    if (t < BNODES) hist[t] = 0;
    __syncthreads();
    for (int i = t; i < n; i += 256) {
        unsigned int w = ebuf[s0 + i];
        slab[i] = w;
        atomicAdd(&hist[w >> 20], 1);
    }
    __syncthreads();
    if (t == 0) {
        int r = 0;
        for (int l = 0; l < BNODES; ++l) { scanx[l] = r; r += hist[l]; }
    }
    __syncthreads();
    if (t < BNODES) {
        cur[t] = scanx[t];
        int v = b * BNODES + t;
        rowptr[v] = s0 + scanx[t];
        if (v < N_NODES) dinv[v] = rsqrtf((float)(hist[t] + 1));
    }
    if (b == 0 && t == 0) rowptr[NBUK * BNODES] = N_EDGES;
    __syncthreads();
    for (int i = t; i < n; i += 256) {
        unsigned int w = slab[i];
        int pos = atomicAdd(&cur[w >> 20], 1);
        slab2[pos] = w;
    }
    __syncthreads();
    for (int i = t; i < n; i += 256) ebuf[s0 + i] = slab2[i];
}

// y1[v][c] = dinv[v] * sum_k x[v][k] * W1[k][c]; 8 nodes x 32 cols per block
__launch_bounds__(256)
__global__ void k_gemm1(const float* __restrict__ x, const float* __restrict__ W1,
                        const float* __restrict__ dinv, float* __restrict__ y1) {
    __shared__ float Wl[DIM * HID];
    for (int i = threadIdx.x; i < DIM * HID; i += 256) Wl[i] = W1[i];
    __syncthreads();
    int node = blockIdx.x * 8 + (threadIdx.x >> 5);
    int col = threadIdx.x & 31;
    if (node >= N_NODES) return;
    const float4* x4 = (const float4*)(x + (size_t)node * DIM);
    float acc = 0.0f;
    #pragma unroll
    for (int k4 = 0; k4 < DIM / 4; ++k4) {
        float4 v = x4[k4];
        int k = k4 * 4;
        acc = fmaf(v.x, Wl[(k + 0) * HID + col], acc);
        acc = fmaf(v.y, Wl[(k + 1) * HID + col], acc);
        acc = fmaf(v.z, Wl[(k + 2) * HID + col], acc);
        acc = fmaf(v.w, Wl[(k + 3) * HID + col], acc);
    }
    y1[(size_t)node * HID + col] = dinv[node] * acc;
}

// Layer-1 gather, CSR-style, register accumulation, NO LDS.
// 32-lane group per node, lane = col. Per batch of 8 edges: ONE broadcast edge-word
// load (lane&7 spreads 8 consecutive words), addresses derived via __shfl (VALU, not
// memory) -> 8 INDEPENDENT contiguous 128B row loads in flight. Round-3..5 failure
// (address-chained load pairs, vmcnt serialization) is structurally impossible here.
__launch_bounds__(256)
__global__ void k_gather1(const int* __restrict__ rowptr, const unsigned int* __restrict__ ebuf,
                          const float* __restrict__ y1, const float* __restrict__ dinv,
                          const float* __restrict__ b1, const float* __restrict__ W2,
                          float* __restrict__ out_h, float* __restrict__ y2) {
    int t = threadIdx.x;
    int node = blockIdx.x * 8 + (t >> 5);
    int col = t & 31;
    if (node >= N_NODES) return;
    int start = rowptr[node], end = rowptr[node + 1];
    float a0 = 0.f, a1 = 0.f, a2 = 0.f, a3 = 0.f;
    float a4 = 0.f, a5 = 0.f, a6 = 0.f, a7 = 0.f;
    int j = start;
    for (; j + 8 <= end; j += 8) {
        unsigned int w = ebuf[j + (col & 7)];     // 8 consecutive words, merged
        unsigned int u0 = __shfl(w, 0, 32) & 0xFFFFF;
        unsigned int u1 = __shfl(w, 1, 32) & 0xFFFFF;
        unsigned int u2 = __shfl(w, 2, 32) & 0xFFFFF;
        unsigned int u3 = __shfl(w, 3, 32) & 0xFFFFF;
        unsigned int u4 = __shfl(w, 4, 32) & 0xFFFFF;
        unsigned int u5 = __shfl(w, 5, 32) & 0xFFFFF;
        unsigned int u6 = __shfl(w, 6, 32) & 0xFFFFF;
        unsigned int u7 = __shfl(w, 7, 32) & 0xFFFFF;
        a0 += y1[(size_t)u0 * HID + col];          // 8 independent 128B row loads
        a1 += y1[(size_t)u1 * HID + col];
        a2 += y1[(size_t)u2 * HID + col];
        a3 += y1[(size_t)u3 * HID + col];
        a4 += y1[(size_t)u4 * HID + col];
        a5 += y1[(size_t)u5 * HID + col];
        a6 += y1[(size_t)u6 * HID + col];
        a7 += y1[(size_t)u7 * HID + col];
    }
    if (j < end) {                                 // masked tail batch (1..7 edges)
        int navail = end - j;
        unsigned int w = ebuf[min(j + (col & 7), end - 1)];
        #pragma unroll
        for (int k = 0; k < 7; ++k) {
            if (k < navail) {
                unsigned int u = __shfl(w, k, 32) & 0xFFFFF;
                a0 += y1[(size_t)u * HID + col];
            }
        }
    }
    float acc = ((a0 + a1) + (a2 + a3)) + ((a4 + a5) + (a6 + a7));
    acc += y1[(size_t)node * HID + col];           // self loop
    float di = dinv[node];
    float h = fmaxf(fmaf(di, acc, b1[col]), 0.f);
    out_h[(size_t)node * HID + col] = h;
    float p = h * W2[col];
    #pragma unroll
    for (int off = 16; off > 0; off >>= 1) p += __shfl_xor(p, off);  // within 32-group
    if (col == 0) y2[node] = di * p;
}

// Layer-2 gather, CSR-style: 32 lanes stride the node's edge run (coalesced ebuf reads).
__launch_bounds__(256)
__global__ void k_gather2(const int* __restrict__ rowptr, const unsigned int* __restrict__ ebuf,
                          const float* __restrict__ y2, const float* __restrict__ dinv,
                          const float* __restrict__ b2, float* __restrict__ scores) {
    int t = threadIdx.x;
    int node = blockIdx.x * 8 + (t >> 5);
    int lane = t & 31;
    if (node >= N_NODES) return;
    int start = rowptr[node], end = rowptr[node + 1];
    float acc = 0.f;
    for (int j = start + lane; j < end; j += 32)
        acc += y2[ebuf[j] & 0xFFFFF];
    #pragma unroll
    for (int off = 16; off > 0; off >>= 1) acc += __shfl_xor(acc, off);
    if (lane == 0) scores[node] = dinv[node] * (acc + y2[node]) + b2[0];
}

extern "C" void kernel_launch(void* const* d_in, const int* in_sizes, int n_in,
                              void* d_out, int out_size, void* d_ws, size_t ws_size,
                              hipStream_t stream) {
    const float* x  = (const float*)d_in[0];
    const int* ei   = (const int*)d_in[1];
    const float* W1 = (const float*)d_in[2];
    const float* b1 = (const float*)d_in[3];
    const float* W2 = (const float*)d_in[4];
    const float* b2 = (const float*)d_in[5];

    const int* src = ei;             // edge_index[0]
    const int* dst = ei + N_EDGES;   // edge_index[1]

    int* bcnt = (int*)d_ws;                             // NBP
    int* boff = bcnt + NBP;                             // NBP
    int* gcur = boff + NBP;                             // NBP
    unsigned int* ebuf = (unsigned int*)(gcur + NBP);   // E
    int* rowptr = (int*)(ebuf + N_EDGES);               // NBUK*BNODES + 4 (padded)
    float* dinv = (float*)(rowptr + NBUK * BNODES + 4); // N
    float* y1   = dinv + N_NODES;                       // N*HID
    float* y2   = y1 + (size_t)N_NODES * HID;           // N

    float* out_h = (float*)d_out;                       // N*HID
    float* out_s = out_h + (size_t)N_NODES * HID;       // N

    k_zeroB <<<NBP / 256, 256, 0, stream>>>(bcnt);
    k_bhist <<<512, 256, 0, stream>>>(dst, bcnt);
    k_bscan <<<1, 256, 0, stream>>>(bcnt, boff, gcur);
    k_bfill <<<NFILL, 256, 0, stream>>>(src, dst, gcur, ebuf);
    k_sort  <<<NBUK, 256, 0, stream>>>(ebuf, boff, bcnt, rowptr, dinv);
    k_gemm1 <<<(N_NODES + 7) / 8, 256, 0, stream>>>(x, W1, dinv, y1);
    k_gather1<<<(N_NODES + 7) / 8, 256, 0, stream>>>(rowptr, ebuf, y1, dinv, b1, W2, out_h, y2);
    k_gather2<<<(N_NODES + 7) / 8, 256, 0, stream>>>(rowptr, ebuf, y2, dinv, b2, out_s);
}

// Round 7
// 193.637 us; speedup vs baseline: 4.4606x; 1.3729x over previous
//
#include <hip/hip_runtime.h>
#include <hip/hip_bf16.h>

#define N_NODES 100000
#define N_EDGES 3200000
#define DIM 128
#define HID 32

#define BSH 6                                   // bucket = dst >> 6
#define BNODES (1 << BSH)                       // 64 nodes per bucket
#define NBUK ((N_NODES + BNODES - 1) >> BSH)    // 1563
#define NBP 2048                                // padded (pow2) bucket count
#define FCHUNK 8192                             // edges per partition block
#define NFILL ((N_EDGES + FCHUNK - 1) / FCHUNK) // 391
#define SLAB 4096                               // per-bucket sort capacity

__device__ __forceinline__ float bf_lo(unsigned int u) {
    return __uint_as_float(u << 16);
}
__device__ __forceinline__ float bf_hi(unsigned int u) {
    return __uint_as_float(u & 0xFFFF0000u);
}

// Workspace: bcnt[NBP] boff[NBP] gcur[NBP] ebuf[E] rowptr[NBUK*64+4] dinv[N] y1u[N*16] y2[N]

__global__ void k_zeroB(int* __restrict__ bcnt) {
    int i = blockIdx.x * blockDim.x + threadIdx.x;
    if (i < NBP) bcnt[i] = 0;
}

// global bucket histogram via per-block LDS histogram
__launch_bounds__(256)
__global__ void k_bhist(const int* __restrict__ dst, int* __restrict__ bcnt) {
    __shared__ int h[NBP];
    for (int i = threadIdx.x; i < NBP; i += 256) h[i] = 0;
    __syncthreads();
    int stride = gridDim.x * blockDim.x;
    for (int e = blockIdx.x * blockDim.x + threadIdx.x; e < N_EDGES; e += stride)
        atomicAdd(&h[dst[e] >> BSH], 1);
    __syncthreads();
    for (int i = threadIdx.x; i < NBP; i += 256)
        if (h[i]) atomicAdd(&bcnt[i], h[i]);
}

// single block: exclusive scan of bcnt[NBP] -> boff, working copy -> gcur
__global__ void k_bscan(const int* __restrict__ bcnt, int* __restrict__ boff,
                        int* __restrict__ gcur) {
    __shared__ int s[256];
    int t = threadIdx.x;
    int c[8]; int sum = 0;
    #pragma unroll
    for (int k = 0; k < 8; ++k) { c[k] = bcnt[t * 8 + k]; sum += c[k]; }
    s[t] = sum; __syncthreads();
    for (int d = 1; d < 256; d <<= 1) {
        int add = (t >= d) ? s[t - d] : 0;
        __syncthreads();
        s[t] += add;
        __syncthreads();
    }
    int excl = s[t] - sum;
    #pragma unroll
    for (int k = 0; k < 8; ++k) {
        boff[t * 8 + k] = excl;
        gcur[t * 8 + k] = excl;
        excl += c[k];
    }
}

// Partition edges into bucket-ordered ebuf with LDS staging + coalesced flush.
// packed edge = (dst & 63) << 20 | src   (src < 2^17)
__launch_bounds__(256)
__global__ void k_bfill(const int* __restrict__ src, const int* __restrict__ dst,
                        int* __restrict__ gcur, unsigned int* __restrict__ ebuf) {
    __shared__ int cntA[NBP];               // pass-1 counts, then reused as pass-2 cursors
    __shared__ int offA[NBP];               // exclusive offsets within chunk
    __shared__ int baseG[NBP];              // reserved global base per bucket
    __shared__ int ssum[256];
    __shared__ unsigned int stage[FCHUNK];  // 32 KB
    __shared__ unsigned short sbuk[FCHUNK]; // 16 KB: bucket id per stage slot (kills bsearch)
    int t = threadIdx.x;
    int e0 = blockIdx.x * FCHUNK;
    int eN = min(e0 + FCHUNK, N_EDGES) - e0;
    for (int i = t; i < NBP; i += 256) cntA[i] = 0;
    __syncthreads();
    for (int i = t; i < eN; i += 256)
        atomicAdd(&cntA[dst[e0 + i] >> BSH], 1);
    __syncthreads();
    {
        int c[8]; int sum = 0;
        #pragma unroll
        for (int k = 0; k < 8; ++k) { c[k] = cntA[t * 8 + k]; sum += c[k]; }
        ssum[t] = sum; __syncthreads();
        for (int d = 1; d < 256; d <<= 1) {
            int add = (t >= d) ? ssum[t - d] : 0;
            __syncthreads();
            ssum[t] += add;
            __syncthreads();
        }
        int excl = ssum[t] - sum;
        #pragma unroll
        for (int k = 0; k < 8; ++k) { offA[t * 8 + k] = excl; excl += c[k]; }
    }
    __syncthreads();
    for (int b = t; b < NBP; b += 256)
        if (cntA[b] > 0) baseG[b] = atomicAdd(&gcur[b], cntA[b]);
    __syncthreads();
    for (int i = t; i < NBP; i += 256) cntA[i] = 0;
    __syncthreads();
    for (int i = t; i < eN; i += 256) {
        int d = dst[e0 + i];
        int b = d >> BSH;
        unsigned int packed = ((unsigned int)(d & (BNODES - 1)) << 20)
                            | (unsigned int)src[e0 + i];
        int pos = offA[b] + atomicAdd(&cntA[b], 1);
        stage[pos] = packed;
        sbuk[pos] = (unsigned short)b;
    }
    __syncthreads();
    for (int i = t; i < eN; i += 256) {
        int b = sbuk[i];
        ebuf[baseG[b] + (i - offA[b])] = stage[i];
    }
}

// Per-bucket LDS counting sort by dlocal -> ebuf globally dst-sorted (CSR order).
// Also emits rowptr[v] (global row starts) and dinv[v] = rsqrt(deg+1).
__launch_bounds__(256)
__global__ void k_sort(unsigned int* __restrict__ ebuf, const int* __restrict__ boff,
                       const int* __restrict__ bcnt, int* __restrict__ rowptr,
                       float* __restrict__ dinv) {
    __shared__ unsigned int slab[SLAB];    // 16 KB
    __shared__ unsigned int slab2[SLAB];   // 16 KB
    __shared__ int hist[BNODES];
    __shared__ int scanx[BNODES];
    __shared__ int cur[BNODES];
    int t = threadIdx.x;
    int b = blockIdx.x;
    int s0 = boff[b];
    int n = min(bcnt[b], SLAB);
    if (t < BNODES) hist[t] = 0;
    __syncthreads();
    for (int i = t; i < n; i += 256) {
        unsigned int w = ebuf[s0 + i];
        slab[i] = w;
        atomicAdd(&hist[w >> 20], 1);
    }
    __syncthreads();
    if (t == 0) {
        int r = 0;
        for (int l = 0; l < BNODES; ++l) { scanx[l] = r; r += hist[l]; }
    }
    __syncthreads();
    if (t < BNODES) {
        cur[t] = scanx[t];
        int v = b * BNODES + t;
        rowptr[v] = s0 + scanx[t];
        if (v < N_NODES) dinv[v] = rsqrtf((float)(hist[t] + 1));
    }
    if (b == 0 && t == 0) rowptr[NBUK * BNODES] = N_EDGES;
    __syncthreads();
    for (int i = t; i < n; i += 256) {
        unsigned int w = slab[i];
        int pos = atomicAdd(&cur[w >> 20], 1);
        slab2[pos] = w;
    }
    __syncthreads();
    for (int i = t; i < n; i += 256) ebuf[s0 + i] = slab2[i];
}

// y1u[v][c] = packed bf16 pair of dinv[v] * (x[v] @ W1)[2c, 2c+1].
// 16 lanes per node (col pairs), 16 nodes per block.
__launch_bounds__(256)
__global__ void k_gemm1(const float* __restrict__ x, const float* __restrict__ W1,
                        const float* __restrict__ dinv, unsigned int* __restrict__ y1u) {
    __shared__ float Wl[DIM * HID];
    for (int i = threadIdx.x; i < DIM * HID; i += 256) Wl[i] = W1[i];
    __syncthreads();
    int node = blockIdx.x * 16 + (threadIdx.x >> 4);
    int c = threadIdx.x & 15;             // col pair: cols 2c, 2c+1
    if (node >= N_NODES) return;
    const float4* x4 = (const float4*)(x + (size_t)node * DIM);
    float a0 = 0.f, a1 = 0.f;
    #pragma unroll
    for (int k4 = 0; k4 < DIM / 4; ++k4) {
        float4 v = x4[k4];                // broadcast across the 16 lanes of a node
        int k = k4 * 4;
        float2 w0 = *(const float2*)&Wl[(k + 0) * HID + 2 * c];  // banks 2c,2c+1: clean
        float2 w1 = *(const float2*)&Wl[(k + 1) * HID + 2 * c];
        float2 w2 = *(const float2*)&Wl[(k + 2) * HID + 2 * c];
        float2 w3 = *(const float2*)&Wl[(k + 3) * HID + 2 * c];
        a0 = fmaf(v.x, w0.x, a0); a1 = fmaf(v.x, w0.y, a1);
        a0 = fmaf(v.y, w1.x, a0); a1 = fmaf(v.y, w1.y, a1);
        a0 = fmaf(v.z, w2.x, a0); a1 = fmaf(v.z, w2.y, a1);
        a0 = fmaf(v.w, w3.x, a0); a1 = fmaf(v.w, w3.y, a1);
    }
    float di = dinv[node];
    __hip_bfloat162 pk = __float22bfloat162_rn(make_float2(a0 * di, a1 * di));
    y1u[node * 16 + c] = *(unsigned int*)&pk;   // 16 lanes -> 64 B row, coalesced
}

// Layer-1 gather, CSR-style, bf16 rows (64 B = 1 line/edge), register accumulation.
// 32 lanes per node = 2 edge-halves x 16 col-pair lanes. Batch of 16 edges:
// ONE broadcast ebuf load feeds 8 INDEPENDENT row loads (each serving 2 edges).
__launch_bounds__(256)
__global__ void k_gather1(const int* __restrict__ rowptr, const unsigned int* __restrict__ ebuf,
                          const unsigned int* __restrict__ y1u, const float* __restrict__ dinv,
                          const float* __restrict__ b1, const float* __restrict__ W2,
                          float* __restrict__ out_h, float* __restrict__ y2) {
    int t = threadIdx.x;
    int node = blockIdx.x * 8 + (t >> 5);
    if (node >= N_NODES) return;
    int lane = t & 31;
    int half = lane >> 4;                 // which edge of each pair this lane serves
    int c = lane & 15;                    // uint index within row (cols 2c, 2c+1)
    int start = rowptr[node], end = rowptr[node + 1];
    float l0 = 0.f, l1 = 0.f, l2 = 0.f, l3 = 0.f;
    float h0 = 0.f, h1 = 0.f, h2 = 0.f, h3 = 0.f;
    int j = start;
    for (; j + 16 <= end; j += 16) {
        unsigned int w = ebuf[j + (lane & 15)];      // 16 consecutive words, merged
        unsigned int e0 = (unsigned int)__shfl((int)w, 0  + half, 32) & 0xFFFFF;
        unsigned int e1 = (unsigned int)__shfl((int)w, 2  + half, 32) & 0xFFFFF;
        unsigned int e2 = (unsigned int)__shfl((int)w, 4  + half, 32) & 0xFFFFF;
        unsigned int e3 = (unsigned int)__shfl((int)w, 6  + half, 32) & 0xFFFFF;
        unsigned int e4 = (unsigned int)__shfl((int)w, 8  + half, 32) & 0xFFFFF;
        unsigned int e5 = (unsigned int)__shfl((int)w, 10 + half, 32) & 0xFFFFF;
        unsigned int e6 = (unsigned int)__shfl((int)w, 12 + half, 32) & 0xFFFFF;
        unsigned int e7 = (unsigned int)__shfl((int)w, 14 + half, 32) & 0xFFFFF;
        unsigned int v0 = y1u[(size_t)e0 * 16 + c];  // 8 independent 64B row loads
        unsigned int v1 = y1u[(size_t)e1 * 16 + c];
        unsigned int v2 = y1u[(size_t)e2 * 16 + c];
        unsigned int v3 = y1u[(size_t)e3 * 16 + c];
        unsigned int v4 = y1u[(size_t)e4 * 16 + c];
        unsigned int v5 = y1u[(size_t)e5 * 16 + c];
        unsigned int v6 = y1u[(size_t)e6 * 16 + c];
        unsigned int v7 = y1u[(size_t)e7 * 16 + c];
        l0 += bf_lo(v0); h0 += bf_hi(v0);
        l1 += bf_lo(v1); h1 += bf_hi(v1);
        l2 += bf_lo(v2); h2 += bf_hi(v2);
        l3 += bf_lo(v3); h3 += bf_hi(v3);
        l0 += bf_lo(v4); h0 += bf_hi(v4);
        l1 += bf_lo(v5); h1 += bf_hi(v5);
        l2 += bf_lo(v6); h2 += bf_hi(v6);
        l3 += bf_lo(v7); h3 += bf_hi(v7);
    }
    int navail = end - j;                 // 0..15 tail edges, processed by half 0
    if (navail > 0) {
        unsigned int w = ebuf[min(j + (lane & 15), end - 1)];
        #pragma unroll
        for (int k = 0; k < 15; ++k) {
            unsigned int u = (unsigned int)__shfl((int)w, k, 32) & 0xFFFFF;
            if (k < navail && half == 0) {
                unsigned int v = y1u[(size_t)u * 16 + c];
                l0 += bf_lo(v); h0 += bf_hi(v);
            }
        }
    }
    float alo = (l0 + l1) + (l2 + l3);
    float ahi = (h0 + h1) + (h2 + h3);
    alo += __shfl_xor(alo, 16, 32);       // combine edge-halves
    ahi += __shfl_xor(ahi, 16, 32);
    unsigned int sv = y1u[(size_t)node * 16 + c];   // self loop
    alo += bf_lo(sv); ahi += bf_hi(sv);
    float di = dinv[node];
    float hlo = fmaxf(fmaf(di, alo, b1[2 * c]), 0.f);
    float hhi = fmaxf(fmaf(di, ahi, b1[2 * c + 1]), 0.f);
    float p = hlo * W2[2 * c] + hhi * W2[2 * c + 1];
    #pragma unroll
    for (int off = 8; off > 0; off >>= 1) p += __shfl_xor(p, off, 16);  // within 16-lane half
    if (half == 0) {
        *(float2*)&out_h[(size_t)node * HID + 2 * c] = make_float2(hlo, hhi);
        if (c == 0) y2[node] = di * p;
    }
}

// Layer-2 gather, CSR-style: 32 lanes stride the node's edge run (coalesced ebuf reads).
__launch_bounds__(256)
__global__ void k_gather2(const int* __restrict__ rowptr, const unsigned int* __restrict__ ebuf,
                          const float* __restrict__ y2, const float* __restrict__ dinv,
                          const float* __restrict__ b2, float* __restrict__ scores) {
    int t = threadIdx.x;
    int node = blockIdx.x * 8 + (t >> 5);
    int lane = t & 31;
    if (node >= N_NODES) return;
    int start = rowptr[node], end = rowptr[node + 1];
    float acc = 0.f;
    for (int j = start + lane; j < end; j += 32)
        acc += y2[ebuf[j] & 0xFFFFF];
    #pragma unroll
    for (int off = 16; off > 0; off >>= 1) acc += __shfl_xor(acc, off);
    if (lane == 0) scores[node] = dinv[node] * (acc + y2[node]) + b2[0];
}

extern "C" void kernel_launch(void* const* d_in, const int* in_sizes, int n_in,
                              void* d_out, int out_size, void* d_ws, size_t ws_size,
                              hipStream_t stream) {
    const float* x  = (const float*)d_in[0];
    const int* ei   = (const int*)d_in[1];
    const float* W1 = (const float*)d_in[2];
    const float* b1 = (const float*)d_in[3];
    const float* W2 = (const float*)d_in[4];
    const float* b2 = (const float*)d_in[5];

    const int* src = ei;             // edge_index[0]
    const int* dst = ei + N_EDGES;   // edge_index[1]

    int* bcnt = (int*)d_ws;                             // NBP
    int* boff = bcnt + NBP;                             // NBP
    int* gcur = boff + NBP;                             // NBP
    unsigned int* ebuf = (unsigned int*)(gcur + NBP);   // E
    int* rowptr = (int*)(ebuf + N_EDGES);               // NBUK*BNODES + 4 (padded)
    float* dinv = (float*)(rowptr + NBUK * BNODES + 4); // N
    unsigned int* y1u = (unsigned int*)(dinv + N_NODES);// N*16 (bf16-packed rows)
    float* y2   = (float*)(y1u + (size_t)N_NODES * 16); // N

    float* out_h = (float*)d_out;                       // N*HID
    float* out_s = out_h + (size_t)N_NODES * HID;       // N

    k_zeroB <<<NBP / 256, 256, 0, stream>>>(bcnt);
    k_bhist <<<512, 256, 0, stream>>>(dst, bcnt);
    k_bscan <<<1, 256, 0, stream>>>(bcnt, boff, gcur);
    k_bfill <<<NFILL, 256, 0, stream>>>(src, dst, gcur, ebuf);
    k_sort  <<<NBUK, 256, 0, stream>>>(ebuf, boff, bcnt, rowptr, dinv);
    k_gemm1 <<<(N_NODES + 15) / 16, 256, 0, stream>>>(x, W1, dinv, y1u);
    k_gather1<<<(N_NODES + 7) / 8, 256, 0, stream>>>(rowptr, ebuf, y1u, dinv, b1, W2, out_h, y2);
    k_gather2<<<(N_NODES + 7) / 8, 256, 0, stream>>>(rowptr, ebuf, y2, dinv, b2, out_s);
}

// Round 8
// 186.041 us; speedup vs baseline: 4.6428x; 1.0408x over previous
//
#include <hip/hip_runtime.h>
#include <hip/hip_bf16.h>

#define N_NODES 100000
#define N_EDGES 3200000
#define DIM 128
#define HID 32

#define BSH 6                                   // bucket = dst >> 6
#define BNODES (1 << BSH)                       // 64 nodes per bucket
#define NBUK ((N_NODES + BNODES - 1) >> BSH)    // 1563
#define NBP 2048                                // padded (pow2) bucket count
#define FCHUNK 4096                             // edges per partition block (49KB LDS -> 3 blk/CU)
#define NFILL ((N_EDGES + FCHUNK - 1) / FCHUNK) // 782
#define SLAB 3072                               // per-bucket sort cap (mean 2048, +22 sigma)

typedef short v8s __attribute__((ext_vector_type(8)));
typedef float v4f __attribute__((ext_vector_type(4)));

__device__ __forceinline__ float bf_lo(unsigned int u) { return __uint_as_float(u << 16); }
__device__ __forceinline__ float bf_hi(unsigned int u) { return __uint_as_float(u & 0xFFFF0000u); }
__device__ __forceinline__ unsigned int pk2(float a, float b) {
    __hip_bfloat162 p = __float22bfloat162_rn(make_float2(a, b));
    union { __hip_bfloat162 h; unsigned int u; } cv; cv.h = p; return cv.u;
}

// Workspace: bcnt[NBP] boff[NBP] gcur[NBP] ebuf[E] rowptr[NBUK*64+4] dinv[N] y1u[N*16] y2[N]

__global__ void k_zeroB(int* __restrict__ bcnt) {
    int i = blockIdx.x * blockDim.x + threadIdx.x;
    if (i < NBP) bcnt[i] = 0;
}

// global bucket histogram via per-block LDS histogram
__launch_bounds__(256)
__global__ void k_bhist(const int* __restrict__ dst, int* __restrict__ bcnt) {
    __shared__ int h[NBP];
    for (int i = threadIdx.x; i < NBP; i += 256) h[i] = 0;
    __syncthreads();
    int stride = gridDim.x * blockDim.x;
    for (int e = blockIdx.x * blockDim.x + threadIdx.x; e < N_EDGES; e += stride)
        atomicAdd(&h[dst[e] >> BSH], 1);
    __syncthreads();
    for (int i = threadIdx.x; i < NBP; i += 256)
        if (h[i]) atomicAdd(&bcnt[i], h[i]);
}

// single block: exclusive scan of bcnt[NBP] -> boff, working copy -> gcur
__global__ void k_bscan(const int* __restrict__ bcnt, int* __restrict__ boff,
                        int* __restrict__ gcur) {
    __shared__ int s[256];
    int t = threadIdx.x;
    int c[8]; int sum = 0;
    #pragma unroll
    for (int k = 0; k < 8; ++k) { c[k] = bcnt[t * 8 + k]; sum += c[k]; }
    s[t] = sum; __syncthreads();
    for (int d = 1; d < 256; d <<= 1) {
        int add = (t >= d) ? s[t - d] : 0;
        __syncthreads();
        s[t] += add;
        __syncthreads();
    }
    int excl = s[t] - sum;
    #pragma unroll
    for (int k = 0; k < 8; ++k) {
        boff[t * 8 + k] = excl;
        gcur[t * 8 + k] = excl;
        excl += c[k];
    }
}

// Partition edges into bucket-ordered ebuf with LDS staging + coalesced flush.
// packed edge = (dst & 63) << 20 | src   (src < 2^17)
__launch_bounds__(256)
__global__ void k_bfill(const int* __restrict__ src, const int* __restrict__ dst,
                        int* __restrict__ gcur, unsigned int* __restrict__ ebuf) {
    __shared__ int cntA[NBP];               // pass-1 counts, then reused as pass-2 cursors
    __shared__ int offA[NBP];               // exclusive offsets within chunk
    __shared__ int baseG[NBP];              // reserved global base per bucket
    __shared__ int ssum[256];
    __shared__ unsigned int stage[FCHUNK];  // 16 KB
    __shared__ unsigned short sbuk[FCHUNK]; // 8 KB: bucket id per stage slot
    int t = threadIdx.x;
    int e0 = blockIdx.x * FCHUNK;
    int eN = min(e0 + FCHUNK, N_EDGES) - e0;
    for (int i = t; i < NBP; i += 256) cntA[i] = 0;
    __syncthreads();
    for (int i = t; i < eN; i += 256)
        atomicAdd(&cntA[dst[e0 + i] >> BSH], 1);
    __syncthreads();
    {
        int c[8]; int sum = 0;
        #pragma unroll
        for (int k = 0; k < 8; ++k) { c[k] = cntA[t * 8 + k]; sum += c[k]; }
        ssum[t] = sum; __syncthreads();
        for (int d = 1; d < 256; d <<= 1) {
            int add = (t >= d) ? ssum[t - d] : 0;
            __syncthreads();
            ssum[t] += add;
            __syncthreads();
        }
        int excl = ssum[t] - sum;
        #pragma unroll
        for (int k = 0; k < 8; ++k) { offA[t * 8 + k] = excl; excl += c[k]; }
    }
    __syncthreads();
    for (int b = t; b < NBP; b += 256)
        if (cntA[b] > 0) baseG[b] = atomicAdd(&gcur[b], cntA[b]);
    __syncthreads();
    for (int i = t; i < NBP; i += 256) cntA[i] = 0;
    __syncthreads();
    for (int i = t; i < eN; i += 256) {
        int d = dst[e0 + i];
        int b = d >> BSH;
        unsigned int packed = ((unsigned int)(d & (BNODES - 1)) << 20)
                            | (unsigned int)src[e0 + i];
        int pos = offA[b] + atomicAdd(&cntA[b], 1);
        stage[pos] = packed;
        sbuk[pos] = (unsigned short)b;
    }
    __syncthreads();
    for (int i = t; i < eN; i += 256) {
        int b = sbuk[i];
        ebuf[baseG[b] + (i - offA[b])] = stage[i];
    }
}

// Per-bucket LDS counting sort by dlocal -> ebuf globally dst-sorted (CSR order).
// Also emits rowptr[v] (global row starts) and dinv[v] = rsqrt(deg+1).
__launch_bounds__(256)
__global__ void k_sort(unsigned int* __restrict__ ebuf, const int* __restrict__ boff,
                       const int* __restrict__ bcnt, int* __restrict__ rowptr,
                       float* __restrict__ dinv) {
    __shared__ unsigned int slab[SLAB];    // 12 KB
    __shared__ unsigned int slab2[SLAB];   // 12 KB
    __shared__ int hist[BNODES];
    __shared__ int scanx[BNODES];
    __shared__ int cur[BNODES];
    int t = threadIdx.x;
    int b = blockIdx.x;
    int s0 = boff[b];
    int n = min(bcnt[b], SLAB);
    if (t < BNODES) hist[t] = 0;
    __syncthreads();
    for (int i = t; i < n; i += 256) {
        unsigned int w = ebuf[s0 + i];
        slab[i] = w;
        atomicAdd(&hist[w >> 20], 1);
    }
    __syncthreads();
    if (t == 0) {
        int r = 0;
        for (int l = 0; l < BNODES; ++l) { scanx[l] = r; r += hist[l]; }
    }
    __syncthreads();
    if (t < BNODES) {
        cur[t] = scanx[t];
        int v = b * BNODES + t;
        rowptr[v] = s0 + scanx[t];
        if (v < N_NODES) dinv[v] = rsqrtf((float)(hist[t] + 1));
    }
    if (b == 0 && t == 0) rowptr[NBUK * BNODES] = N_EDGES;
    __syncthreads();
    for (int i = t; i < n; i += 256) {
        unsigned int w = slab[i];
        int pos = atomicAdd(&cur[w >> 20], 1);
        slab2[pos] = w;
    }
    __syncthreads();
    for (int i = t; i < n; i += 256) ebuf[s0 + i] = slab2[i];
}

// y1u = bf16-packed rows of dinv[v] * (x @ W1), via MFMA 16x16x32 bf16.
// Wave = one 16-node tile per iter: A = x rows (fp32->bf16 in reg, no LDS),
// B = W1 bf16 fragments held in registers across the grid-stride loop.
// Layouts (guide-verified): A/B: m/n = lane&15, k-block = lane>>4 (8 k each);
// C: col = lane&15, row = (lane>>4)*4 + reg.
__launch_bounds__(256)
__global__ void k_gemm1(const float* __restrict__ x, const float* __restrict__ W1,
                        const float* __restrict__ dinv, unsigned int* __restrict__ y1u) {
    int wv = (blockIdx.x * 256 + threadIdx.x) >> 6;
    int nwaves = (gridDim.x * 256) >> 6;
    int lane = threadIdx.x & 63;
    int m = lane & 15;
    int kb = lane >> 4;                   // 0..3
    // B fragments: [ntile][kstep]
    v8s Bf[2][4];
    #pragma unroll
    for (int tt = 0; tt < 2; ++tt)
        #pragma unroll
        for (int s = 0; s < 4; ++s) {
            union { unsigned int u[4]; v8s v; } ub;
            #pragma unroll
            for (int jj = 0; jj < 4; ++jj) {
                int k = s * 32 + kb * 8 + jj * 2;
                ub.u[jj] = pk2(W1[k * HID + tt * 16 + m], W1[(k + 1) * HID + tt * 16 + m]);
            }
            Bf[tt][s] = ub.v;
        }
    for (int tile = wv; tile < N_NODES / 16; tile += nwaves) {   // 6250 exact, no tail
        int base = tile * 16;
        const float* xr = x + (size_t)(base + m) * DIM;
        v4f acc0 = {0.f, 0.f, 0.f, 0.f}, acc1 = {0.f, 0.f, 0.f, 0.f};
        #pragma unroll
        for (int s = 0; s < 4; ++s) {
            float4 xa = *(const float4*)(xr + s * 32 + kb * 8);
            float4 xb = *(const float4*)(xr + s * 32 + kb * 8 + 4);
            union { unsigned int u[4]; v8s v; } ua;
            ua.u[0] = pk2(xa.x, xa.y); ua.u[1] = pk2(xa.z, xa.w);
            ua.u[2] = pk2(xb.x, xb.y); ua.u[3] = pk2(xb.z, xb.w);
            acc0 = __builtin_amdgcn_mfma_f32_16x16x32_bf16(ua.v, Bf[0][s], acc0, 0, 0, 0);
            acc1 = __builtin_amdgcn_mfma_f32_16x16x32_bf16(ua.v, Bf[1][s], acc1, 0, 0, 0);
        }
        float4 dv = *(const float4*)(dinv + base + kb * 4);     // rows kb*4..kb*4+3
        float d[4] = {dv.x, dv.y, dv.z, dv.w};
        #pragma unroll
        for (int r = 0; r < 4; ++r) {
            float v0 = acc0[r] * d[r];
            float v1 = acc1[r] * d[r];
            float p0 = __shfl_xor(v0, 1, 64);                   // partner col
            float p1 = __shfl_xor(v1, 1, 64);
            if ((m & 1) == 0) {
                int node = base + kb * 4 + r;
                y1u[node * 16 + (m >> 1)] = pk2(v0, p0);        // cols m, m+1
                y1u[node * 16 + 8 + (m >> 1)] = pk2(v1, p1);    // cols 16+m, 17+m
            }
        }
    }
}

// Layer-1 gather, CSR-style, bf16 rows (64 B = 1 line/edge), register accumulation.
// 32 lanes per node = 2 edge-halves x 16 col-pair lanes. Batch of 16 edges:
// ONE broadcast ebuf load feeds 8 INDEPENDENT row loads (each serving 2 edges).
__launch_bounds__(256)
__global__ void k_gather1(const int* __restrict__ rowptr, const unsigned int* __restrict__ ebuf,
                          const unsigned int* __restrict__ y1u, const float* __restrict__ dinv,
                          const float* __restrict__ b1, const float* __restrict__ W2,
                          float* __restrict__ out_h, float* __restrict__ y2) {
    int t = threadIdx.x;
    int node = blockIdx.x * 8 + (t >> 5);
    if (node >= N_NODES) return;
    int lane = t & 31;
    int half = lane >> 4;                 // which edge of each pair this lane serves
    int c = lane & 15;                    // uint index within row (cols 2c, 2c+1)
    int start = rowptr[node], end = rowptr[node + 1];
    float l0 = 0.f, l1 = 0.f, l2 = 0.f, l3 = 0.f;
    float h0 = 0.f, h1 = 0.f, h2 = 0.f, h3 = 0.f;
    int j = start;
    for (; j + 16 <= end; j += 16) {
        unsigned int w = ebuf[j + (lane & 15)];      // 16 consecutive words, merged
        unsigned int e0 = (unsigned int)__shfl((int)w, 0  + half, 32) & 0xFFFFF;
        unsigned int e1 = (unsigned int)__shfl((int)w, 2  + half, 32) & 0xFFFFF;
        unsigned int e2 = (unsigned int)__shfl((int)w, 4  + half, 32) & 0xFFFFF;
        unsigned int e3 = (unsigned int)__shfl((int)w, 6  + half, 32) & 0xFFFFF;
        unsigned int e4 = (unsigned int)__shfl((int)w, 8  + half, 32) & 0xFFFFF;
        unsigned int e5 = (unsigned int)__shfl((int)w, 10 + half, 32) & 0xFFFFF;
        unsigned int e6 = (unsigned int)__shfl((int)w, 12 + half, 32) & 0xFFFFF;
        unsigned int e7 = (unsigned int)__shfl((int)w, 14 + half, 32) & 0xFFFFF;
        unsigned int v0 = y1u[(size_t)e0 * 16 + c];  // 8 independent 64B row loads
        unsigned int v1 = y1u[(size_t)e1 * 16 + c];
        unsigned int v2 = y1u[(size_t)e2 * 16 + c];
        unsigned int v3 = y1u[(size_t)e3 * 16 + c];
        unsigned int v4 = y1u[(size_t)e4 * 16 + c];
        unsigned int v5 = y1u[(size_t)e5 * 16 + c];
        unsigned int v6 = y1u[(size_t)e6 * 16 + c];
        unsigned int v7 = y1u[(size_t)e7 * 16 + c];
        l0 += bf_lo(v0); h0 += bf_hi(v0);
        l1 += bf_lo(v1); h1 += bf_hi(v1);
        l2 += bf_lo(v2); h2 += bf_hi(v2);
        l3 += bf_lo(v3); h3 += bf_hi(v3);
        l0 += bf_lo(v4); h0 += bf_hi(v4);
        l1 += bf_lo(v5); h1 += bf_hi(v5);
        l2 += bf_lo(v6); h2 += bf_hi(v6);
        l3 += bf_lo(v7); h3 += bf_hi(v7);
    }
    int navail = end - j;                 // 0..15 tail edges, split across both halves
    if (navail > 0) {
        unsigned int w = ebuf[min(j + (lane & 15), end - 1)];
        #pragma unroll
        for (int k = 0; k < 8; ++k) {
            int idx = k + 8 * half;
            unsigned int u = (unsigned int)__shfl((int)w, idx, 32) & 0xFFFFF;
            if (idx < navail) {
                unsigned int v = y1u[(size_t)u * 16 + c];
                l0 += bf_lo(v); h0 += bf_hi(v);
            }
        }
    }
    float alo = (l0 + l1) + (l2 + l3);
    float ahi = (h0 + h1) + (h2 + h3);
    alo += __shfl_xor(alo, 16, 32);       // combine edge-halves
    ahi += __shfl_xor(ahi, 16, 32);
    unsigned int sv = y1u[(size_t)node * 16 + c];   // self loop
    alo += bf_lo(sv); ahi += bf_hi(sv);
    float di = dinv[node];
    float hlo = fmaxf(fmaf(di, alo, b1[2 * c]), 0.f);
    float hhi = fmaxf(fmaf(di, ahi, b1[2 * c + 1]), 0.f);
    float p = hlo * W2[2 * c] + hhi * W2[2 * c + 1];
    #pragma unroll
    for (int off = 8; off > 0; off >>= 1) p += __shfl_xor(p, off, 16);  // within 16-lane half
    if (half == 0) {
        *(float2*)&out_h[(size_t)node * HID + 2 * c] = make_float2(hlo, hhi);
        if (c == 0) y2[node] = di * p;
    }
}

// Layer-2 gather, CSR-style: 32 lanes stride the node's edge run (coalesced ebuf reads).
__launch_bounds__(256)
__global__ void k_gather2(const int* __restrict__ rowptr, const unsigned int* __restrict__ ebuf,
                          const float* __restrict__ y2, const float* __restrict__ dinv,
                          const float* __restrict__ b2, float* __restrict__ scores) {
    int t = threadIdx.x;
    int node = blockIdx.x * 8 + (t >> 5);
    int lane = t & 31;
    if (node >= N_NODES) return;
    int start = rowptr[node], end = rowptr[node + 1];
    float acc = 0.f;
    for (int j = start + lane; j < end; j += 32)
        acc += y2[ebuf[j] & 0xFFFFF];
    #pragma unroll
    for (int off = 16; off > 0; off >>= 1) acc += __shfl_xor(acc, off);
    if (lane == 0) scores[node] = dinv[node] * (acc + y2[node]) + b2[0];
}

extern "C" void kernel_launch(void* const* d_in, const int* in_sizes, int n_in,
                              void* d_out, int out_size, void* d_ws, size_t ws_size,
                              hipStream_t stream) {
    const float* x  = (const float*)d_in[0];
    const int* ei   = (const int*)d_in[1];
    const float* W1 = (const float*)d_in[2];
    const float* b1 = (const float*)d_in[3];
    const float* W2 = (const float*)d_in[4];
    const float* b2 = (const float*)d_in[5];

    const int* src = ei;             // edge_index[0]
    const int* dst = ei + N_EDGES;   // edge_index[1]

    int* bcnt = (int*)d_ws;                             // NBP
    int* boff = bcnt + NBP;                             // NBP
    int* gcur = boff + NBP;                             // NBP
    unsigned int* ebuf = (unsigned int*)(gcur + NBP);   // E
    int* rowptr = (int*)(ebuf + N_EDGES);               // NBUK*BNODES + 4 (padded)
    float* dinv = (float*)(rowptr + NBUK * BNODES + 4); // N
    unsigned int* y1u = (unsigned int*)(dinv + N_NODES);// N*16 (bf16-packed rows)
    float* y2   = (float*)(y1u + (size_t)N_NODES * 16); // N

    float* out_h = (float*)d_out;                       // N*HID
    float* out_s = out_h + (size_t)N_NODES * HID;       // N

    k_zeroB <<<NBP / 256, 256, 0, stream>>>(bcnt);
    k_bhist <<<512, 256, 0, stream>>>(dst, bcnt);
    k_bscan <<<1, 256, 0, stream>>>(bcnt, boff, gcur);
    k_bfill <<<NFILL, 256, 0, stream>>>(src, dst, gcur, ebuf);
    k_sort  <<<NBUK, 256, 0, stream>>>(ebuf, boff, bcnt, rowptr, dinv);
    k_gemm1 <<<512, 256, 0, stream>>>(x, W1, dinv, y1u);
    k_gather1<<<(N_NODES + 7) / 8, 256, 0, stream>>>(rowptr, ebuf, y1u, dinv, b1, W2, out_h, y2);
    k_gather2<<<(N_NODES + 7) / 8, 256, 0, stream>>>(rowptr, ebuf, y2, dinv, b2, out_s);
}

// Round 9
// 178.900 us; speedup vs baseline: 4.8281x; 1.0399x over previous
//
#include <hip/hip_runtime.h>
#include <hip/hip_bf16.h>

#define N_NODES 100000
#define N_EDGES 3200000
#define DIM 128
#define HID 32

#define BSH 6                                   // bucket = dst >> 6
#define BNODES (1 << BSH)                       // 64 nodes per bucket
#define NBUK ((N_NODES + BNODES - 1) >> BSH)    // 1563
#define NBP 2048                                // padded (pow2) bucket count
#define FCHUNK 8192                             // edges per partition block (72KB LDS, 2 blk/CU)
#define NFILL ((N_EDGES + FCHUNK - 1) / FCHUNK) // 391
#define SLAB 3072                               // per-bucket sort cap (mean 2048, +22 sigma)

typedef short v8s __attribute__((ext_vector_type(8)));
typedef float v4f __attribute__((ext_vector_type(4)));

__device__ __forceinline__ float bf_lo(unsigned int u) { return __uint_as_float(u << 16); }
__device__ __forceinline__ float bf_hi(unsigned int u) { return __uint_as_float(u & 0xFFFF0000u); }
__device__ __forceinline__ unsigned int pk2(float a, float b) {
    __hip_bfloat162 p = __float22bfloat162_rn(make_float2(a, b));
    union { __hip_bfloat162 h; unsigned int u; } cv; cv.h = p; return cv.u;
}

// Workspace: bcnt[NBP] boff[NBP] gcur[NBP] ebuf[E] rowptr[NBUK*64+4] dinv[N]
//            y1a[N*8] y1b[N*8] pA[N] y2[N]

__global__ void k_zeroB(int* __restrict__ bcnt) {
    int i = blockIdx.x * blockDim.x + threadIdx.x;
    if (i < NBP) bcnt[i] = 0;
}

// global bucket histogram via per-block LDS histogram (int4 edge reads)
__launch_bounds__(256)
__global__ void k_bhist(const int* __restrict__ dst, int* __restrict__ bcnt) {
    __shared__ int h[NBP];
    for (int i = threadIdx.x; i < NBP; i += 256) h[i] = 0;
    __syncthreads();
    const int4* d4 = (const int4*)dst;
    int stride = gridDim.x * blockDim.x;
    for (int e = blockIdx.x * blockDim.x + threadIdx.x; e < N_EDGES / 4; e += stride) {
        int4 v = d4[e];
        atomicAdd(&h[v.x >> BSH], 1);
        atomicAdd(&h[v.y >> BSH], 1);
        atomicAdd(&h[v.z >> BSH], 1);
        atomicAdd(&h[v.w >> BSH], 1);
    }
    __syncthreads();
    for (int i = threadIdx.x; i < NBP; i += 256)
        if (h[i]) atomicAdd(&bcnt[i], h[i]);
}

// single block: exclusive scan of bcnt[NBP] -> boff, working copy -> gcur
__global__ void k_bscan(const int* __restrict__ bcnt, int* __restrict__ boff,
                        int* __restrict__ gcur) {
    __shared__ int s[256];
    int t = threadIdx.x;
    int c[8]; int sum = 0;
    #pragma unroll
    for (int k = 0; k < 8; ++k) { c[k] = bcnt[t * 8 + k]; sum += c[k]; }
    s[t] = sum; __syncthreads();
    for (int d = 1; d < 256; d <<= 1) {
        int add = (t >= d) ? s[t - d] : 0;
        __syncthreads();
        s[t] += add;
        __syncthreads();
    }
    int excl = s[t] - sum;
    #pragma unroll
    for (int k = 0; k < 8; ++k) {
        boff[t * 8 + k] = excl;
        gcur[t * 8 + k] = excl;
        excl += c[k];
    }
}

// Partition edges into bucket-ordered ebuf with LDS staging + coalesced flush.
// packed edge = (dst & 63) << 20 | src   (src < 2^17)
__launch_bounds__(256)
__global__ void k_bfill(const int* __restrict__ src, const int* __restrict__ dst,
                        int* __restrict__ gcur, unsigned int* __restrict__ ebuf) {
    __shared__ int cntA[NBP];               // pass-1 counts, then reused as pass-2 cursors
    __shared__ int offA[NBP];               // exclusive offsets within chunk
    __shared__ int baseG[NBP];              // reserved global base per bucket
    __shared__ int ssum[256];
    __shared__ unsigned int stage[FCHUNK];  // 32 KB
    __shared__ unsigned short sbuk[FCHUNK]; // 16 KB: bucket id per stage slot
    int t = threadIdx.x;
    int e0 = blockIdx.x * FCHUNK;
    int eN = min(e0 + FCHUNK, N_EDGES) - e0;
    for (int i = t; i < NBP; i += 256) cntA[i] = 0;
    __syncthreads();
    for (int i = t; i < eN; i += 256)
        atomicAdd(&cntA[dst[e0 + i] >> BSH], 1);
    __syncthreads();
    {
        int c[8]; int sum = 0;
        #pragma unroll
        for (int k = 0; k < 8; ++k) { c[k] = cntA[t * 8 + k]; sum += c[k]; }
        ssum[t] = sum; __syncthreads();
        for (int d = 1; d < 256; d <<= 1) {
            int add = (t >= d) ? ssum[t - d] : 0;
            __syncthreads();
            ssum[t] += add;
            __syncthreads();
        }
        int excl = ssum[t] - sum;
        #pragma unroll
        for (int k = 0; k < 8; ++k) { offA[t * 8 + k] = excl; excl += c[k]; }
    }
    __syncthreads();
    for (int b = t; b < NBP; b += 256)
        if (cntA[b] > 0) baseG[b] = atomicAdd(&gcur[b], cntA[b]);
    __syncthreads();
    for (int i = t; i < NBP; i += 256) cntA[i] = 0;
    __syncthreads();
    for (int i = t; i < eN; i += 256) {
        int d = dst[e0 + i];
        int b = d >> BSH;
        unsigned int packed = ((unsigned int)(d & (BNODES - 1)) << 20)
                            | (unsigned int)src[e0 + i];
        int pos = offA[b] + atomicAdd(&cntA[b], 1);
        stage[pos] = packed;
        sbuk[pos] = (unsigned short)b;
    }
    __syncthreads();
    for (int i = t; i < eN; i += 256) {
        int b = sbuk[i];
        ebuf[baseG[b] + (i - offA[b])] = stage[i];
    }
}

// Per-bucket LDS counting sort by dlocal -> ebuf globally dst-sorted (CSR order).
// Also emits rowptr[v] (global row starts) and dinv[v] = rsqrt(deg+1).
__launch_bounds__(256)
__global__ void k_sort(unsigned int* __restrict__ ebuf, const int* __restrict__ boff,
                       const int* __restrict__ bcnt, int* __restrict__ rowptr,
                       float* __restrict__ dinv) {
    __shared__ unsigned int slab[SLAB];    // 12 KB
    __shared__ unsigned int slab2[SLAB];   // 12 KB
    __shared__ int hist[BNODES];
    __shared__ int scanx[BNODES];
    __shared__ int cur[BNODES];
    int t = threadIdx.x;
    int b = blockIdx.x;
    int s0 = boff[b];
    int n = min(bcnt[b], SLAB);
    if (t < BNODES) hist[t] = 0;
    __syncthreads();
    for (int i = t; i < n; i += 256) {
        unsigned int w = ebuf[s0 + i];
        slab[i] = w;
        atomicAdd(&hist[w >> 20], 1);
    }
    __syncthreads();
    if (t == 0) {
        int r = 0;
        for (int l = 0; l < BNODES; ++l) { scanx[l] = r; r += hist[l]; }
    }
    __syncthreads();
    if (t < BNODES) {
        cur[t] = scanx[t];
        int v = b * BNODES + t;
        rowptr[v] = s0 + scanx[t];
        if (v < N_NODES) dinv[v] = rsqrtf((float)(hist[t] + 1));
    }
    if (b == 0 && t == 0) rowptr[NBUK * BNODES] = N_EDGES;
    __syncthreads();
    for (int i = t; i < n; i += 256) {
        unsigned int w = slab[i];
        int pos = atomicAdd(&cur[w >> 20], 1);
        slab2[pos] = w;
    }
    __syncthreads();
    for (int i = t; i < n; i += 256) ebuf[s0 + i] = slab2[i];
}

// y1 = bf16-packed rows of dinv[v] * (x @ W1), via MFMA 16x16x32 bf16.
// Column-split output: y1a = cols 0..15 (32B rows), y1b = cols 16..31.
__launch_bounds__(256)
__global__ void k_gemm1(const float* __restrict__ x, const float* __restrict__ W1,
                        const float* __restrict__ dinv, unsigned int* __restrict__ y1a,
                        unsigned int* __restrict__ y1b) {
    int wv = (blockIdx.x * 256 + threadIdx.x) >> 6;
    int nwaves = (gridDim.x * 256) >> 6;
    int lane = threadIdx.x & 63;
    int m = lane & 15;
    int kb = lane >> 4;                   // 0..3
    v8s Bf[2][4];                         // B fragments: [ntile][kstep]
    #pragma unroll
    for (int tt = 0; tt < 2; ++tt)
        #pragma unroll
        for (int s = 0; s < 4; ++s) {
            union { unsigned int u[4]; v8s v; } ub;
            #pragma unroll
            for (int jj = 0; jj < 4; ++jj) {
                int k = s * 32 + kb * 8 + jj * 2;
                ub.u[jj] = pk2(W1[k * HID + tt * 16 + m], W1[(k + 1) * HID + tt * 16 + m]);
            }
            Bf[tt][s] = ub.v;
        }
    for (int tile = wv; tile < N_NODES / 16; tile += nwaves) {   // 6250 exact, no tail
        int base = tile * 16;
        const float* xr = x + (size_t)(base + m) * DIM;
        v4f acc0 = {0.f, 0.f, 0.f, 0.f}, acc1 = {0.f, 0.f, 0.f, 0.f};
        #pragma unroll
        for (int s = 0; s < 4; ++s) {
            float4 xa = *(const float4*)(xr + s * 32 + kb * 8);
            float4 xb = *(const float4*)(xr + s * 32 + kb * 8 + 4);
            union { unsigned int u[4]; v8s v; } ua;
            ua.u[0] = pk2(xa.x, xa.y); ua.u[1] = pk2(xa.z, xa.w);
            ua.u[2] = pk2(xb.x, xb.y); ua.u[3] = pk2(xb.z, xb.w);
            acc0 = __builtin_amdgcn_mfma_f32_16x16x32_bf16(ua.v, Bf[0][s], acc0, 0, 0, 0);
            acc1 = __builtin_amdgcn_mfma_f32_16x16x32_bf16(ua.v, Bf[1][s], acc1, 0, 0, 0);
        }
        float4 dv = *(const float4*)(dinv + base + kb * 4);     // rows kb*4..kb*4+3
        float d[4] = {dv.x, dv.y, dv.z, dv.w};
        #pragma unroll
        for (int r = 0; r < 4; ++r) {
            float v0 = acc0[r] * d[r];
            float v1 = acc1[r] * d[r];
            float p0 = __shfl_xor(v0, 1, 64);                   // partner col
            float p1 = __shfl_xor(v1, 1, 64);
            if ((m & 1) == 0) {
                int node = base + kb * 4 + r;
                y1a[node * 8 + (m >> 1)] = pk2(v0, p0);         // cols m, m+1
                y1b[node * 8 + (m >> 1)] = pk2(v1, p1);         // cols 16+m, 17+m
            }
        }
    }
}

// Layer-1 gather over an L2-RESIDENT half-table (3.2MB): 32 lanes per node =
// 4 edge-subsets x 8 uint-lanes; batch of 32 edges per broadcast ebuf load,
// 8 independent 32B row loads in flight. HALF=0: cols 0..15 -> out_h, pA.
// HALF=1: cols 16..31 -> out_h, y2 = dinv*(pA + pB).
template <int HALF>
__launch_bounds__(256)
__global__ void k_gather1(const int* __restrict__ rowptr, const unsigned int* __restrict__ ebuf,
                          const unsigned int* __restrict__ yh, const float* __restrict__ dinv,
                          const float* __restrict__ b1, const float* __restrict__ W2,
                          float* __restrict__ out_h, float* __restrict__ pA,
                          float* __restrict__ y2) {
    int t = threadIdx.x;
    int node = blockIdx.x * 8 + (t >> 5);
    if (node >= N_NODES) return;
    int lane = t & 31;
    int sub = lane >> 3;                  // edge subset 0..3
    int c = lane & 7;                     // uint index in 32B row (cols 2c, 2c+1)
    int start = rowptr[node], end = rowptr[node + 1];
    float l0 = 0.f, l1 = 0.f, l2 = 0.f, l3 = 0.f;
    float h0 = 0.f, h1 = 0.f, h2 = 0.f, h3 = 0.f;
    int j = start;
    for (; j + 32 <= end; j += 32) {
        unsigned int w = ebuf[j + lane];             // 32 consecutive words
        unsigned int e0 = (unsigned int)__shfl((int)w, 0  + sub, 32) & 0xFFFFF;
        unsigned int e1 = (unsigned int)__shfl((int)w, 4  + sub, 32) & 0xFFFFF;
        unsigned int e2 = (unsigned int)__shfl((int)w, 8  + sub, 32) & 0xFFFFF;
        unsigned int e3 = (unsigned int)__shfl((int)w, 12 + sub, 32) & 0xFFFFF;
        unsigned int e4 = (unsigned int)__shfl((int)w, 16 + sub, 32) & 0xFFFFF;
        unsigned int e5 = (unsigned int)__shfl((int)w, 20 + sub, 32) & 0xFFFFF;
        unsigned int e6 = (unsigned int)__shfl((int)w, 24 + sub, 32) & 0xFFFFF;
        unsigned int e7 = (unsigned int)__shfl((int)w, 28 + sub, 32) & 0xFFFFF;
        unsigned int v0 = yh[(size_t)e0 * 8 + c];    // 8 independent 32B row loads
        unsigned int v1 = yh[(size_t)e1 * 8 + c];
        unsigned int v2 = yh[(size_t)e2 * 8 + c];
        unsigned int v3 = yh[(size_t)e3 * 8 + c];
        unsigned int v4 = yh[(size_t)e4 * 8 + c];
        unsigned int v5 = yh[(size_t)e5 * 8 + c];
        unsigned int v6 = yh[(size_t)e6 * 8 + c];
        unsigned int v7 = yh[(size_t)e7 * 8 + c];
        l0 += bf_lo(v0); h0 += bf_hi(v0);
        l1 += bf_lo(v1); h1 += bf_hi(v1);
        l2 += bf_lo(v2); h2 += bf_hi(v2);
        l3 += bf_lo(v3); h3 += bf_hi(v3);
        l0 += bf_lo(v4); h0 += bf_hi(v4);
        l1 += bf_lo(v5); h1 += bf_hi(v5);
        l2 += bf_lo(v6); h2 += bf_hi(v6);
        l3 += bf_lo(v7); h3 += bf_hi(v7);
    }
    int navail = end - j;                 // 0..31 tail edges
    if (navail > 0) {
        unsigned int w = ebuf[min(j + lane, end - 1)];
        #pragma unroll
        for (int k = 0; k < 8; ++k) {
            int idx = k * 4 + sub;
            unsigned int u = (unsigned int)__shfl((int)w, idx, 32) & 0xFFFFF;
            if (idx < navail) {
                unsigned int v = yh[(size_t)u * 8 + c];
                l0 += bf_lo(v); h0 += bf_hi(v);
            }
        }
    }
    float alo = (l0 + l1) + (l2 + l3);
    float ahi = (h0 + h1) + (h2 + h3);
    alo += __shfl_xor(alo, 8, 32);        // combine edge subsets
    ahi += __shfl_xor(ahi, 8, 32);
    alo += __shfl_xor(alo, 16, 32);
    ahi += __shfl_xor(ahi, 16, 32);
    unsigned int sv = yh[(size_t)node * 8 + c];      // self loop
    alo += bf_lo(sv); ahi += bf_hi(sv);
    float di = dinv[node];
    int col = HALF * 16 + 2 * c;
    float hlo = fmaxf(fmaf(di, alo, b1[col]), 0.f);
    float hhi = fmaxf(fmaf(di, ahi, b1[col + 1]), 0.f);
    float p = hlo * W2[col] + hhi * W2[col + 1];
    p += __shfl_xor(p, 1, 32);
    p += __shfl_xor(p, 2, 32);
    p += __shfl_xor(p, 4, 32);            // sum over 8 col-lanes (subsets identical)
    if (sub == 0) {
        *(float2*)&out_h[(size_t)node * HID + col] = make_float2(hlo, hhi);
        if (c == 0) {
            if (HALF == 0) pA[node] = p;
            else           y2[node] = di * (pA[node] + p);
        }
    }
}

// Layer-2 gather, CSR-style: 32 lanes stride the node's edge run (coalesced ebuf reads).
__launch_bounds__(256)
__global__ void k_gather2(const int* __restrict__ rowptr, const unsigned int* __restrict__ ebuf,
                          const float* __restrict__ y2, const float* __restrict__ dinv,
                          const float* __restrict__ b2, float* __restrict__ scores) {
    int t = threadIdx.x;
    int node = blockIdx.x * 8 + (t >> 5);
    int lane = t & 31;
    if (node >= N_NODES) return;
    int start = rowptr[node], end = rowptr[node + 1];
    float acc = 0.f;
    for (int j = start + lane; j < end; j += 32)
        acc += y2[ebuf[j] & 0xFFFFF];
    #pragma unroll
    for (int off = 16; off > 0; off >>= 1) acc += __shfl_xor(acc, off);
    if (lane == 0) scores[node] = dinv[node] * (acc + y2[node]) + b2[0];
}

extern "C" void kernel_launch(void* const* d_in, const int* in_sizes, int n_in,
                              void* d_out, int out_size, void* d_ws, size_t ws_size,
                              hipStream_t stream) {
    const float* x  = (const float*)d_in[0];
    const int* ei   = (const int*)d_in[1];
    const float* W1 = (const float*)d_in[2];
    const float* b1 = (const float*)d_in[3];
    const float* W2 = (const float*)d_in[4];
    const float* b2 = (const float*)d_in[5];

    const int* src = ei;             // edge_index[0]
    const int* dst = ei + N_EDGES;   // edge_index[1]

    int* bcnt = (int*)d_ws;                             // NBP
    int* boff = bcnt + NBP;                             // NBP
    int* gcur = boff + NBP;                             // NBP
    unsigned int* ebuf = (unsigned int*)(gcur + NBP);   // E
    int* rowptr = (int*)(ebuf + N_EDGES);               // NBUK*BNODES + 4
    float* dinv = (float*)(rowptr + NBUK * BNODES + 4); // N
    unsigned int* y1a = (unsigned int*)(dinv + N_NODES);// N*8 (bf16 cols 0..15)
    unsigned int* y1b = y1a + (size_t)N_NODES * 8;      // N*8 (bf16 cols 16..31)
    float* pA   = (float*)(y1b + (size_t)N_NODES * 8);  // N
    float* y2   = pA + N_NODES;                         // N

    float* out_h = (float*)d_out;                       // N*HID
    float* out_s = out_h + (size_t)N_NODES * HID;       // N

    k_zeroB <<<NBP / 256, 256, 0, stream>>>(bcnt);
    k_bhist <<<512, 256, 0, stream>>>(dst, bcnt);
    k_bscan <<<1, 256, 0, stream>>>(bcnt, boff, gcur);
    k_bfill <<<NFILL, 256, 0, stream>>>(src, dst, gcur, ebuf);
    k_sort  <<<NBUK, 256, 0, stream>>>(ebuf, boff, bcnt, rowptr, dinv);
    k_gemm1 <<<512, 256, 0, stream>>>(x, W1, dinv, y1a, y1b);
    k_gather1<0><<<(N_NODES + 7) / 8, 256, 0, stream>>>(rowptr, ebuf, y1a, dinv, b1, W2, out_h, pA, y2);
    k_gather1<1><<<(N_NODES + 7) / 8, 256, 0, stream>>>(rowptr, ebuf, y1b, dinv, b1, W2, out_h, pA, y2);
    k_gather2<<<(N_NODES + 7) / 8, 256, 0, stream>>>(rowptr, ebuf, y2, dinv, b2, out_s);
}